// Round 5
// baseline (1088.648 us; speedup 1.0000x reference)
//
#include <hip/hip_runtime.h>
#include <hip/hip_fp16.h>
#include <math.h>

constexpr int NN   = 20000;
constexpr int EE   = 320000;
constexpr int ET   = EE + NN;   // 340000 with self loops
constexpr int GG   = 128;
constexpr int DEE  = 64;
constexpr int DD   = 512;
constexpr int OUTD = 256;

using half8 = __attribute__((ext_vector_type(8))) _Float16;
using f32x4 = __attribute__((ext_vector_type(4))) float;

// ---- async global->LDS 16B (wave-uniform LDS base + lane*16 implicit) ----
__device__ __forceinline__ void ldg2lds16(const void* g, void* l) {
  __builtin_amdgcn_global_load_lds((const __attribute__((address_space(1))) unsigned*)g,
                                   (__attribute__((address_space(3))) unsigned*)l, 16, 0, 0);
}

// ---------------- embedding gather -> f16 ----------------
__global__ __launch_bounds__(256) void k_embf16(const int* __restrict__ ids,
                                                const float* __restrict__ emb,
                                                __half* __restrict__ x0) {
  for (int i = blockIdx.x * 256 + threadIdx.x; i < NN * 16; i += gridDim.x * 256) {
    int n = i >> 4, q = (i & 15) * 4;
    float4 v = *(const float4*)(emb + (size_t)ids[n] * DEE + q);
    __half2* o = (__half2*)(x0 + (size_t)n * DEE + q);
    o[0] = __floats2half2_rn(v.x, v.y);
    o[1] = __floats2half2_rn(v.z, v.w);
  }
}

// ---------------- weight transpose + f16 hi/lo split: T[n][k] = W[k][n] ----------------
__global__ __launch_bounds__(256) void k_wsplit16T(const float* __restrict__ W,
                                                   __half* __restrict__ Th, __half* __restrict__ Tl,
                                                   int K, int N) {
  __shared__ float t[32][33];
  int n0 = blockIdx.x * 32, k0 = blockIdx.y * 32;
  int c = threadIdx.x & 31, r4 = threadIdx.x >> 5;
  for (int rr = 0; rr < 32; rr += 8)
    t[rr + r4][c] = W[(size_t)(k0 + rr + r4) * N + n0 + c];
  __syncthreads();
  for (int rr = 0; rr < 32; rr += 8) {
    int n = n0 + rr + r4, k = k0 + c;
    float v = t[c][rr + r4];
    __half hi = __float2half_rn(v);
    Th[(size_t)n * K + k] = hi;
    Tl[(size_t)n * K + k] = __float2half_rn(v - __half2float(hi));
  }
}

// ---------------- graph node-count histogram ----------------
__global__ __launch_bounds__(256) void k_gcnt(const int* __restrict__ batch, int* __restrict__ gcnt) {
  for (int n = blockIdx.x * 256 + threadIdx.x; n < NN; n += gridDim.x * 256)
    atomicAdd(&gcnt[batch[n]], 1);
}

// ---------------- CSR build ----------------
__global__ __launch_bounds__(256) void k_count(const int* __restrict__ ei, int* __restrict__ cnt) {
  for (int k = blockIdx.x * 256 + threadIdx.x; k < ET; k += gridDim.x * 256) {
    int d = (k < EE) ? ei[EE + k] : (k - EE);
    atomicAdd(&cnt[d], 1);
  }
}

__global__ __launch_bounds__(1024) void k_scan(const int* __restrict__ cnt, int* __restrict__ off) {
  __shared__ int part[1024];
  int tid = threadIdx.x;
  constexpr int CH = (NN + 1023) / 1024;  // 20
  int base = tid * CH;
  int s = 0;
  for (int i = 0; i < CH; ++i) { int idx = base + i; if (idx < NN) s += cnt[idx]; }
  part[tid] = s;
  __syncthreads();
  for (int o = 1; o < 1024; o <<= 1) {
    int add = (tid >= o) ? part[tid - o] : 0;
    int v = part[tid];
    __syncthreads();
    part[tid] = v + add;
    __syncthreads();
  }
  int run = (tid == 0) ? 0 : part[tid - 1];
  for (int i = 0; i < CH; ++i) {
    int idx = base + i;
    if (idx < NN) { off[idx] = run; run += cnt[idx]; }
  }
  if (tid == 1023) off[NN] = ET;
}

__global__ __launch_bounds__(256) void k_scatter(const int* __restrict__ ei, const int* __restrict__ off,
                                                 int* __restrict__ cur, int* __restrict__ csrc) {
  for (int k = blockIdx.x * 256 + threadIdx.x; k < ET; k += gridDim.x * 256) {
    int s = (k < EE) ? ei[k]      : (k - EE);
    int d = (k < EE) ? ei[EE + k] : (k - EE);
    int p = atomicAdd(&cur[d], 1);
    csrc[off[d] + p] = s;
  }
}

// ---------------- f16 MFMA GEMM (A single + B hi/lo split): C[M,512] = A[M,K] @ B ----------------
template<int OUT16>
__global__ __launch_bounds__(256) void k_mfma2(const __half* __restrict__ A,
                                               const __half* __restrict__ Bh,
                                               const __half* __restrict__ Bl,
                                               void* __restrict__ Cout, int M, int K) {
  __shared__ __half lds[3 * 128 * 64];   // A | Bh | Bl, 16 KB each
  __half* As  = lds;
  __half* Bhs = lds + 8192;
  __half* Bls = lds + 16384;
  const int tid = threadIdx.x, l = tid & 63, w = tid >> 6;
  const int wr = w >> 1, wc = w & 1;
  const int m0 = blockIdx.y * 128, n0 = blockIdx.x * 128;
  const int l15 = l & 15, l16 = l >> 4;
  const int sr = l >> 3;                 // staging sub-row 0..7
  const int ss = (l & 7) ^ sr;           // staging swizzled 16B slot

  f32x4 acc[4][4] = {};
  for (int k0 = 0; k0 < K; k0 += 64) {
#pragma unroll
    for (int j = 0; j < 4; ++j) {
      int rbase = j * 32 + w * 8;
      int rl = rbase + sr;
      int gA = min(m0 + rl, M - 1);
      int gB = n0 + rl;
      const size_t ko = (size_t)(k0 + ss * 8);
      ldg2lds16(A  + (size_t)gA * K + ko, As  + rbase * 64);
      ldg2lds16(Bh + (size_t)gB * K + ko, Bhs + rbase * 64);
      ldg2lds16(Bl + (size_t)gB * K + ko, Bls + rbase * 64);
    }
    __syncthreads();
#pragma unroll
    for (int kh = 0; kh < 2; ++kh) {
      half8 af[4], bhf[4], blf[4];
#pragma unroll
      for (int t = 0; t < 4; ++t) {
        int ra = wr * 64 + t * 16 + l15;
        int ca = (kh * 4 + l16) ^ (ra & 7);
        af[t] = *(const half8*)(As + ra * 64 + ca * 8);
        int rb = wc * 64 + t * 16 + l15;
        int cb = (kh * 4 + l16) ^ (rb & 7);
        bhf[t] = *(const half8*)(Bhs + rb * 64 + cb * 8);
        blf[t] = *(const half8*)(Bls + rb * 64 + cb * 8);
      }
#pragma unroll
      for (int i = 0; i < 4; ++i)
#pragma unroll
        for (int j = 0; j < 4; ++j) {
          acc[i][j] = __builtin_amdgcn_mfma_f32_16x16x32_f16(af[i], bhf[j], acc[i][j], 0, 0, 0);
          acc[i][j] = __builtin_amdgcn_mfma_f32_16x16x32_f16(af[i], blf[j], acc[i][j], 0, 0, 0);
        }
    }
    __syncthreads();
  }
#pragma unroll
  for (int i = 0; i < 4; ++i) {
#pragma unroll
    for (int r = 0; r < 4; ++r) {
      int row = m0 + wr * 64 + i * 16 + l16 * 4 + r;
      if (row >= M) continue;
#pragma unroll
      for (int j = 0; j < 4; ++j) {
        int col = n0 + wc * 64 + j * 16 + l15;
        float v = acc[i][j][r];
        if (OUT16) ((__half*)Cout)[(size_t)row * DD + col] = __float2half(v);
        else       ((float*)Cout)[(size_t)row * DD + col]  = v;
      }
    }
  }
}

// ---------------- fp32 tiled GEMM 64x64 (MLP head) ----------------
// mode: 1 = +bias, 2 = +bias then exact GELU
__global__ __launch_bounds__(256) void k_gemm(const float* __restrict__ A, const float* __restrict__ B,
                                              float* __restrict__ Cout, const float* __restrict__ bias,
                                              int M, int Nc, int K, int mode) {
  __shared__ float As[16][68];
  __shared__ float Bs[16][68];
  int tid = threadIdx.x;
  int m0 = blockIdx.x * 64, n0 = blockIdx.y * 64;
  int tx = tid & 15, ty = tid >> 4;
  int lam = tid >> 2, lak = (tid & 3) * 4;
  int lbk = tid >> 4, lbn = (tid & 15) * 4;
  float acc[4][4] = {};
  int ar = m0 + lam;
  for (int k0 = 0; k0 < K; k0 += 16) {
    float4 av;
    if (ar < M) av = *(const float4*)(A + (size_t)ar * K + k0 + lak);
    else        av = make_float4(0.f, 0.f, 0.f, 0.f);
    As[lak + 0][lam] = av.x; As[lak + 1][lam] = av.y;
    As[lak + 2][lam] = av.z; As[lak + 3][lam] = av.w;
    *(float4*)&Bs[lbk][lbn] = *(const float4*)(B + (size_t)(k0 + lbk) * Nc + n0 + lbn);
    __syncthreads();
#pragma unroll
    for (int kk = 0; kk < 16; ++kk) {
      const float4 a4 = *(const float4*)&As[kk][ty << 2];
      const float4 b4 = *(const float4*)&Bs[kk][tx << 2];
      const float a[4] = {a4.x, a4.y, a4.z, a4.w};
      const float b[4] = {b4.x, b4.y, b4.z, b4.w};
#pragma unroll
      for (int i = 0; i < 4; ++i)
#pragma unroll
        for (int j = 0; j < 4; ++j)
          acc[i][j] = fmaf(a[i], b[j], acc[i][j]);
    }
    __syncthreads();
  }
#pragma unroll
  for (int i = 0; i < 4; ++i) {
    int row = m0 + ty * 4 + i;
    if (row >= M) continue;
#pragma unroll
    for (int j = 0; j < 4; ++j) {
      int col = n0 + tx * 4 + j;
      float v = acc[i][j] + bias[col];
      if (mode == 2) v = 0.5f * v * (1.0f + erff(v * 0.70710678118654752f));
      Cout[(size_t)row * Nc + col] = v;
    }
  }
}

// ---------------- attention score dots from fp16 xp: s_src/s_dst [N,4] ----------------
__global__ __launch_bounds__(256) void k_sdots(const __half* __restrict__ xp16,
                                               const float* __restrict__ asw,
                                               const float* __restrict__ adw,
                                               float* __restrict__ ssrc, float* __restrict__ sdst) {
  int wv = threadIdx.x >> 6, ln = threadIdx.x & 63;
  int n = blockIdx.x * 4 + wv;
  int h = ln >> 4, c0 = (ln & 15) * 8;
  uint4 raw = *(const uint4*)(xp16 + (size_t)n * DD + h * 128 + c0);
  const __half2* hp = (const __half2*)&raw;
  float a = 0.f, b = 0.f;
#pragma unroll
  for (int j = 0; j < 4; ++j) {
    float2 f = __half22float2(hp[j]);
    a += f.x * asw[h * 128 + c0 + 2 * j]     + f.y * asw[h * 128 + c0 + 2 * j + 1];
    b += f.x * adw[h * 128 + c0 + 2 * j]     + f.y * adw[h * 128 + c0 + 2 * j + 1];
  }
#pragma unroll
  for (int o = 8; o; o >>= 1) { a += __shfl_xor(a, o); b += __shfl_xor(b, o); }
  if ((ln & 15) == 0) { ssrc[n * 4 + h] = a; sdst[n * 4 + h] = b; }
}

__device__ __forceinline__ void acc8(float* acc, float w, const uint4& r) {
  const __half2* hp = (const __half2*)&r;
#pragma unroll
  for (int j = 0; j < 4; ++j) {
    float2 f = __half22float2(hp[j]);
    acc[2 * j]     += w * f.x;
    acc[2 * j + 1] += w * f.y;
  }
}

// ---------------- wave-per-node single-pass softmax aggregation ----------------
// No segment_max: alpha = exp(e)/sum(exp(e)) is exactly the same ratio; |e| << 88
// with LN-scaled features so fp32 exp cannot overflow. One pass: den & acc fused.
__global__ __launch_bounds__(256) void k_agg(const __half* __restrict__ xp16,
                                             const float* __restrict__ ssrc,
                                             const float* __restrict__ sdst,
                                             const int* __restrict__ off,
                                             const int* __restrict__ csr,
                                             const int* __restrict__ batch,
                                             const float* __restrict__ bias,
                                             float* __restrict__ xio,   // in: residual, out: pre-LN
                                             float* __restrict__ gsum, float* __restrict__ gsq) {
  int wv = threadIdx.x >> 6, ln = threadIdx.x & 63;
  int n = blockIdx.x * 4 + wv;         // NN % 4 == 0
  int beg = off[n], end = off[n + 1];
  int h = ln >> 4;
  const int d = ln * 8;

  float sdh = sdst[n * 4 + h];

  // prefetch residual + bias early (independent of edge chain)
  float4 b0 = *(const float4*)(bias + d);
  float4 b1 = *(const float4*)(bias + d + 4);
  float4 r0v = *(const float4*)(xio + (size_t)n * DD + d);
  float4 r1v = *(const float4*)(xio + (size_t)n * DD + d + 4);

  float acc[8] = {};
  float den = 0.f;

  int k = beg;
  for (; k + 8 <= end; k += 8) {
    int sk[8];
#pragma unroll
    for (int u = 0; u < 8; ++u) sk[u] = csr[k + u];
    uint4 r[8];
#pragma unroll
    for (int u = 0; u < 8; ++u) r[u] = *(const uint4*)(xp16 + (size_t)sk[u] * DD + d);
    float w[8];
#pragma unroll
    for (int u = 0; u < 8; ++u) {
      float e = ssrc[sk[u] * 4 + h] + sdh;
      e = (e > 0.f) ? e : 0.2f * e;
      w[u] = __expf(e);
    }
#pragma unroll
    for (int u = 0; u < 8; ++u) { den += w[u]; acc8(acc, w[u], r[u]); }
  }
  if (k + 4 <= end) {
    int sk[4];
#pragma unroll
    for (int u = 0; u < 4; ++u) sk[u] = csr[k + u];
    uint4 r[4];
#pragma unroll
    for (int u = 0; u < 4; ++u) r[u] = *(const uint4*)(xp16 + (size_t)sk[u] * DD + d);
#pragma unroll
    for (int u = 0; u < 4; ++u) {
      float e = ssrc[sk[u] * 4 + h] + sdh;
      e = (e > 0.f) ? e : 0.2f * e;
      float wu = __expf(e);
      den += wu; acc8(acc, wu, r[u]);
    }
    k += 4;
  }
  for (; k < end; ++k) {
    int sk = csr[k];
    uint4 r = *(const uint4*)(xp16 + (size_t)sk * DD + d);
    float e = ssrc[sk * 4 + h] + sdh;
    e = (e > 0.f) ? e : 0.2f * e;
    float wu = __expf(e);
    den += wu; acc8(acc, wu, r);
  }

  float inv = 1.0f / den;
  float bv[8] = {b0.x,b0.y,b0.z,b0.w,b1.x,b1.y,b1.z,b1.w};
  float rv[8] = {r0v.x,r0v.y,r0v.z,r0v.w,r1v.x,r1v.y,r1v.z,r1v.w};
  float o[8];
  float ps = 0.f, pq = 0.f;
#pragma unroll
  for (int i = 0; i < 8; ++i) {
    o[i] = acc[i] * inv + bv[i] + rv[i];
    ps += o[i];
    pq += o[i] * o[i];
  }
  *(float4*)(xio + (size_t)n * DD + d)     = make_float4(o[0], o[1], o[2], o[3]);
  *(float4*)(xio + (size_t)n * DD + d + 4) = make_float4(o[4], o[5], o[6], o[7]);
#pragma unroll
  for (int oo = 32; oo; oo >>= 1) { ps += __shfl_xor(ps, oo); pq += __shfl_xor(pq, oo); }
  if (ln == 0) {
    int g = batch[n];
    atomicAdd(&gsum[g], ps);
    atomicAdd(&gsq[g], pq);
  }
}

// ---------------- per-graph LN stats ----------------
__global__ void k_stats(const int* __restrict__ gcnt, const float* __restrict__ gsum,
                        const float* __restrict__ gsq, float* __restrict__ gmu, float* __restrict__ grstd) {
  int t = threadIdx.x;
  if (t < GG) {
    float cnt = fmaxf((float)gcnt[t] * (float)DD, 1.0f);
    float mu  = gsum[t] / cnt;
    float var = gsq[t] / cnt - mu * mu;
    var = fmaxf(var, 0.0f);
    gmu[t]   = mu;
    grstd[t] = rsqrtf(var + 1e-5f);
  }
}

// ---------------- graph-LN normalize + optional f16 write (next GEMM's A) ----------------
__global__ __launch_bounds__(256) void k_norm(float* __restrict__ x, const int* __restrict__ batch,
                                              const float* __restrict__ gmu, const float* __restrict__ grstd,
                                              const float* __restrict__ lnw, const float* __restrict__ lnb,
                                              __half* __restrict__ xh, int wf16) {
  for (int i4 = blockIdx.x * 256 + threadIdx.x; i4 < NN * DD / 4; i4 += gridDim.x * 256) {
    int i = i4 * 4;
    int n = i >> 9, d = i & 511;
    int g = batch[n];
    float mu = gmu[g], rs = grstd[g];
    float4 v = *(float4*)(x + i);
    float4 w = *(const float4*)(lnw + d);
    float4 b = *(const float4*)(lnb + d);
    v.x = (v.x - mu) * rs * w.x + b.x;
    v.y = (v.y - mu) * rs * w.y + b.y;
    v.z = (v.z - mu) * rs * w.z + b.z;
    v.w = (v.w - mu) * rs * w.w + b.w;
    *(float4*)(x + i) = v;
    if (wf16) {
      __half2* o = (__half2*)(xh + i);
      o[0] = __floats2half2_rn(v.x, v.y);
      o[1] = __floats2half2_rn(v.z, v.w);
    }
  }
}

// ---------------- pooling: mean + max per graph (batch_vec sorted) ----------------
__device__ __forceinline__ int lowb(const int* a, int n, int key) {
  int lo = 0, hi = n;
  while (lo < hi) { int mid = (lo + hi) >> 1; if (a[mid] < key) lo = mid + 1; else hi = mid; }
  return lo;
}

__global__ __launch_bounds__(256) void k_pool(const float* __restrict__ x, const int* __restrict__ batch,
                                              float* __restrict__ pool) {
  int g = blockIdx.x, tid = threadIdx.x;
  __shared__ int sb, se;
  if (tid == 0) { sb = lowb(batch, NN, g); se = lowb(batch, NN, g + 1); }
  __syncthreads();
  int b = sb, e = se;
  float s0 = 0.f, s1 = 0.f, m0 = -INFINITY, m1 = -INFINITY;
  for (int n = b; n < e; ++n) {
    float v0 = x[(size_t)n * DD + tid];
    float v1 = x[(size_t)n * DD + tid + 256];
    s0 += v0; s1 += v1;
    m0 = fmaxf(m0, v0); m1 = fmaxf(m1, v1);
  }
  int cnt = e - b;
  float inv = 1.0f / (float)(cnt > 0 ? cnt : 1);
  pool[(size_t)g * 1024 + tid]             = s0 * inv;
  pool[(size_t)g * 1024 + tid + 256]       = s1 * inv;
  pool[(size_t)g * 1024 + 512 + tid]       = (cnt > 0) ? m0 : 0.f;
  pool[(size_t)g * 1024 + 512 + tid + 256] = (cnt > 0) ? m1 : 0.f;
}

// ---------------- final row L2 normalize ----------------
__global__ __launch_bounds__(256) void k_l2(float* __restrict__ h) {
  int g = blockIdx.x, t = threadIdx.x;
  float v = h[(size_t)g * OUTD + t];
  float q = v * v;
#pragma unroll
  for (int o = 32; o; o >>= 1) q += __shfl_xor(q, o);
  __shared__ float w[4];
  int wv = t >> 6, ln = t & 63;
  if (ln == 0) w[wv] = q;
  __syncthreads();
  float tot = w[0] + w[1] + w[2] + w[3];
  float nrm = fmaxf(sqrtf(tot), 1e-12f);
  h[(size_t)g * OUTD + t] = v / nrm;
}

// ---------------- launcher ----------------
extern "C" void kernel_launch(void* const* d_in, const int* in_sizes, int n_in,
                              void* d_out, int out_size, void* d_ws, size_t ws_size,
                              hipStream_t stream) {
  const int*   node_ids = (const int*)d_in[0];
  const int*   ei       = (const int*)d_in[1];
  const int*   batch    = (const int*)d_in[2];
  const float* emb      = (const float*)d_in[3];
  const float* W[4]  = {(const float*)d_in[4],  (const float*)d_in[10], (const float*)d_in[16], (const float*)d_in[22]};
  const float* AS[4] = {(const float*)d_in[5],  (const float*)d_in[11], (const float*)d_in[17], (const float*)d_in[23]};
  const float* AD[4] = {(const float*)d_in[6],  (const float*)d_in[12], (const float*)d_in[18], (const float*)d_in[24]};
  const float* BV[4] = {(const float*)d_in[7],  (const float*)d_in[13], (const float*)d_in[19], (const float*)d_in[25]};
  const float* LW[4] = {(const float*)d_in[8],  (const float*)d_in[14], (const float*)d_in[20], (const float*)d_in[26]};
  const float* LB[4] = {(const float*)d_in[9],  (const float*)d_in[15], (const float*)d_in[21], (const float*)d_in[27]};
  const float* res_w0 = (const float*)d_in[28];
  const float* p1w    = (const float*)d_in[29];
  const float* p1b    = (const float*)d_in[30];
  const float* p2w    = (const float*)d_in[31];
  const float* p2b    = (const float*)d_in[32];
  float* out = (float*)d_out;

  char* ws = (char*)d_ws;
  size_t pos = 0;
  auto alloc = [&](size_t bytes) -> char* {
    char* p = ws + pos;
    pos = (pos + bytes + 255) & ~size_t(255);
    return p;
  };
  float*  xb    = (float*)alloc((size_t)NN * DD * 4);
  __half* xh16  = (__half*)alloc((size_t)NN * DD * 2);   // also hosts x0 f16 [NN][64] early
  __half* xp16  = (__half*)alloc((size_t)NN * DD * 2);
  float*  ssrc  = (float*)alloc((size_t)NN * 4 * 4);
  float*  sdst  = (float*)alloc((size_t)NN * 4 * 4);
  int*    coff  = (int*)alloc((size_t)(NN + 1) * 4);
  int*    ccur  = (int*)alloc((size_t)NN * 4);
  int*    csrc  = (int*)alloc((size_t)ET * 4);
  int*    gcnt  = (int*)alloc((size_t)GG * 4);
  float*  gsum  = (float*)alloc((size_t)GG * 4 * 2);
  float*  gsq   = gsum + GG;
  float*  gmu   = (float*)alloc((size_t)GG * 4 * 2);
  float*  grstd = gmu + GG;
  // transposed f16 hi/lo weights
  __half* w0th = (__half*)alloc((size_t)DEE * DD * 2); __half* w0tl = (__half*)alloc((size_t)DEE * DD * 2);
  __half* rwth = (__half*)alloc((size_t)DEE * DD * 2); __half* rwtl = (__half*)alloc((size_t)DEE * DD * 2);
  __half* wth[4] = {w0th, nullptr, nullptr, nullptr};
  __half* wtl[4] = {w0tl, nullptr, nullptr, nullptr};
  for (int i = 1; i < 4; ++i) {
    wth[i] = (__half*)alloc((size_t)DD * DD * 2);
    wtl[i] = (__half*)alloc((size_t)DD * DD * 2);
  }
  float* pool = (float*)alloc((size_t)GG * 1024 * 4);
  float* h1   = (float*)alloc((size_t)GG * 1024 * 4);
  (void)ws_size; (void)in_sizes; (void)n_in; (void)out_size;

  __half* x0f = xh16;   // [NN][64] f16, aliased (dead once L0 GEMMs finish)

  // ---- CSR + histogram + weight prep ----
  hipMemsetAsync(ccur, 0, (size_t)NN * 4, stream);
  hipMemsetAsync(gcnt, 0, (size_t)GG * 4, stream);
  k_embf16<<<1250, 256, 0, stream>>>(node_ids, emb, x0f);
  k_gcnt<<<256, 256, 0, stream>>>(batch, gcnt);
  k_count<<<1024, 256, 0, stream>>>(ei, ccur);
  k_scan<<<1, 1024, 0, stream>>>(ccur, coff);
  hipMemsetAsync(ccur, 0, (size_t)NN * 4, stream);
  k_scatter<<<1024, 256, 0, stream>>>(ei, coff, ccur, csrc);
  k_wsplit16T<<<dim3(16, 2),  256, 0, stream>>>(W[0],   w0th, w0tl, DEE, DD);
  k_wsplit16T<<<dim3(16, 2),  256, 0, stream>>>(res_w0, rwth, rwtl, DEE, DD);
  for (int i = 1; i < 4; ++i)
    k_wsplit16T<<<dim3(16, 16), 256, 0, stream>>>(W[i], wth[i], wtl[i], DD, DD);

  // ---- L0 projections ----
  k_mfma2<1><<<dim3(4, 157), 256, 0, stream>>>(x0f, w0th, w0tl, xp16, NN, DEE);
  k_mfma2<0><<<dim3(4, 157), 256, 0, stream>>>(x0f, rwth, rwtl, xb,   NN, DEE);

  // ---- 4 GAT layers ----
  for (int L = 0; L < 4; ++L) {
    k_sdots<<<NN / 4, 256, 0, stream>>>(xp16, AS[L], AD[L], ssrc, sdst);
    hipMemsetAsync(gsum, 0, (size_t)GG * 8, stream);
    k_agg<<<NN / 4, 256, 0, stream>>>(xp16, ssrc, sdst, coff, csrc, batch, BV[L], xb, gsum, gsq);
    k_stats<<<1, GG, 0, stream>>>(gcnt, gsum, gsq, gmu, grstd);
    k_norm<<<2048, 256, 0, stream>>>(xb, batch, gmu, grstd, LW[L], LB[L], xh16, (L < 3) ? 1 : 0);
    if (L < 3)
      k_mfma2<1><<<dim3(4, 157), 256, 0, stream>>>(xh16, wth[L + 1], wtl[L + 1], xp16, NN, DD);
  }

  // ---- pool + MLP head + normalize ----
  k_pool<<<GG, 256, 0, stream>>>(xb, batch, pool);
  k_gemm<<<dim3(2, 16), 256, 0, stream>>>(pool, p1w, h1, p1b, GG, 1024, 1024, 2);
  k_gemm<<<dim3(2, 4), 256, 0, stream>>>(h1, p2w, out, p2b, GG, OUTD, 1024, 1);
  k_l2<<<GG, 256, 0, stream>>>(out);
}

// Round 6
// 951.772 us; speedup vs baseline: 1.1438x; 1.1438x over previous
//
#include <hip/hip_runtime.h>
#include <hip/hip_fp16.h>
#include <math.h>

constexpr int NN   = 20000;
constexpr int EE   = 320000;
constexpr int ET   = EE + NN;   // 340000 with self loops
constexpr int GG   = 128;
constexpr int DEE  = 64;
constexpr int DD   = 512;
constexpr int OUTD = 256;

using half8 = __attribute__((ext_vector_type(8))) _Float16;
using f32x4 = __attribute__((ext_vector_type(4))) float;

// ---- async global->LDS 16B (wave-uniform LDS base + lane*16 implicit) ----
__device__ __forceinline__ void ldg2lds16(const void* g, void* l) {
  __builtin_amdgcn_global_load_lds((const __attribute__((address_space(1))) unsigned*)g,
                                   (__attribute__((address_space(3))) unsigned*)l, 16, 0, 0);
}

// ---------------- embedding gather -> f16 ----------------
__global__ __launch_bounds__(256) void k_embf16(const int* __restrict__ ids,
                                                const float* __restrict__ emb,
                                                __half* __restrict__ x0) {
  for (int i = blockIdx.x * 256 + threadIdx.x; i < NN * 16; i += gridDim.x * 256) {
    int n = i >> 4, q = (i & 15) * 4;
    float4 v = *(const float4*)(emb + (size_t)ids[n] * DEE + q);
    __half2* o = (__half2*)(x0 + (size_t)n * DEE + q);
    o[0] = __floats2half2_rn(v.x, v.y);
    o[1] = __floats2half2_rn(v.z, v.w);
  }
}

// ---------------- weight transpose + f16 hi/lo split: T[n][k] = W[k][n] ----------------
__global__ __launch_bounds__(256) void k_wsplit16T(const float* __restrict__ W,
                                                   __half* __restrict__ Th, __half* __restrict__ Tl,
                                                   int K, int N) {
  __shared__ float t[32][33];
  int n0 = blockIdx.x * 32, k0 = blockIdx.y * 32;
  int c = threadIdx.x & 31, r4 = threadIdx.x >> 5;
  for (int rr = 0; rr < 32; rr += 8)
    t[rr + r4][c] = W[(size_t)(k0 + rr + r4) * N + n0 + c];
  __syncthreads();
  for (int rr = 0; rr < 32; rr += 8) {
    int n = n0 + rr + r4, k = k0 + c;
    float v = t[c][rr + r4];
    __half hi = __float2half_rn(v);
    Th[(size_t)n * K + k] = hi;
    Tl[(size_t)n * K + k] = __float2half_rn(v - __half2float(hi));
  }
}

// ---------------- CSR build ----------------
__global__ __launch_bounds__(256) void k_count(const int* __restrict__ ei, int* __restrict__ cnt) {
  for (int k = blockIdx.x * 256 + threadIdx.x; k < ET; k += gridDim.x * 256) {
    int d = (k < EE) ? ei[EE + k] : (k - EE);
    atomicAdd(&cnt[d], 1);
  }
}

__global__ __launch_bounds__(1024) void k_scan(const int* __restrict__ cnt, int* __restrict__ off) {
  __shared__ int part[1024];
  int tid = threadIdx.x;
  constexpr int CH = (NN + 1023) / 1024;  // 20
  int base = tid * CH;
  int s = 0;
  for (int i = 0; i < CH; ++i) { int idx = base + i; if (idx < NN) s += cnt[idx]; }
  part[tid] = s;
  __syncthreads();
  for (int o = 1; o < 1024; o <<= 1) {
    int add = (tid >= o) ? part[tid - o] : 0;
    int v = part[tid];
    __syncthreads();
    part[tid] = v + add;
    __syncthreads();
  }
  int run = (tid == 0) ? 0 : part[tid - 1];
  for (int i = 0; i < CH; ++i) {
    int idx = base + i;
    if (idx < NN) { off[idx] = run; run += cnt[idx]; }
  }
  if (tid == 1023) off[NN] = ET;
}

__global__ __launch_bounds__(256) void k_scatter(const int* __restrict__ ei, const int* __restrict__ off,
                                                 int* __restrict__ cur, int* __restrict__ csrc) {
  for (int k = blockIdx.x * 256 + threadIdx.x; k < ET; k += gridDim.x * 256) {
    int s = (k < EE) ? ei[k]      : (k - EE);
    int d = (k < EE) ? ei[EE + k] : (k - EE);
    int p = atomicAdd(&cur[d], 1);
    csrc[off[d] + p] = s;
  }
}

// ---------------- f16 MFMA GEMM (A single + B hi/lo split): C[M,512] = A[M,K] @ B ----------------
template<int OUT16>
__global__ __launch_bounds__(256) void k_mfma2(const __half* __restrict__ A,
                                               const __half* __restrict__ Bh,
                                               const __half* __restrict__ Bl,
                                               void* __restrict__ Cout, int M, int K) {
  __shared__ __half lds[3 * 128 * 64];   // A | Bh | Bl, 16 KB each
  __half* As  = lds;
  __half* Bhs = lds + 8192;
  __half* Bls = lds + 16384;
  const int tid = threadIdx.x, l = tid & 63, w = tid >> 6;
  const int wr = w >> 1, wc = w & 1;
  const int m0 = blockIdx.y * 128, n0 = blockIdx.x * 128;
  const int l15 = l & 15, l16 = l >> 4;
  const int sr = l >> 3;                 // staging sub-row 0..7
  const int ss = (l & 7) ^ sr;           // staging swizzled 16B slot

  f32x4 acc[4][4] = {};
  for (int k0 = 0; k0 < K; k0 += 64) {
#pragma unroll
    for (int j = 0; j < 4; ++j) {
      int rbase = j * 32 + w * 8;
      int rl = rbase + sr;
      int gA = min(m0 + rl, M - 1);
      int gB = n0 + rl;
      const size_t ko = (size_t)(k0 + ss * 8);
      ldg2lds16(A  + (size_t)gA * K + ko, As  + rbase * 64);
      ldg2lds16(Bh + (size_t)gB * K + ko, Bhs + rbase * 64);
      ldg2lds16(Bl + (size_t)gB * K + ko, Bls + rbase * 64);
    }
    __syncthreads();
#pragma unroll
    for (int kh = 0; kh < 2; ++kh) {
      half8 af[4], bhf[4], blf[4];
#pragma unroll
      for (int t = 0; t < 4; ++t) {
        int ra = wr * 64 + t * 16 + l15;
        int ca = (kh * 4 + l16) ^ (ra & 7);
        af[t] = *(const half8*)(As + ra * 64 + ca * 8);
        int rb = wc * 64 + t * 16 + l15;
        int cb = (kh * 4 + l16) ^ (rb & 7);
        bhf[t] = *(const half8*)(Bhs + rb * 64 + cb * 8);
        blf[t] = *(const half8*)(Bls + rb * 64 + cb * 8);
      }
#pragma unroll
      for (int i = 0; i < 4; ++i)
#pragma unroll
        for (int j = 0; j < 4; ++j) {
          acc[i][j] = __builtin_amdgcn_mfma_f32_16x16x32_f16(af[i], bhf[j], acc[i][j], 0, 0, 0);
          acc[i][j] = __builtin_amdgcn_mfma_f32_16x16x32_f16(af[i], blf[j], acc[i][j], 0, 0, 0);
        }
    }
    __syncthreads();
  }
#pragma unroll
  for (int i = 0; i < 4; ++i) {
#pragma unroll
    for (int r = 0; r < 4; ++r) {
      int row = m0 + wr * 64 + i * 16 + l16 * 4 + r;
      if (row >= M) continue;
#pragma unroll
      for (int j = 0; j < 4; ++j) {
        int col = n0 + wc * 64 + j * 16 + l15;
        float v = acc[i][j][r];
        if (OUT16) ((__half*)Cout)[(size_t)row * DD + col] = __float2half(v);
        else       ((float*)Cout)[(size_t)row * DD + col]  = v;
      }
    }
  }
}

// ---------------- fp32 tiled GEMM 64x64 (MLP head) ----------------
// mode: 1 = +bias, 2 = +bias then exact GELU
__global__ __launch_bounds__(256) void k_gemm(const float* __restrict__ A, const float* __restrict__ B,
                                              float* __restrict__ Cout, const float* __restrict__ bias,
                                              int M, int Nc, int K, int mode) {
  __shared__ float As[16][68];
  __shared__ float Bs[16][68];
  int tid = threadIdx.x;
  int m0 = blockIdx.x * 64, n0 = blockIdx.y * 64;
  int tx = tid & 15, ty = tid >> 4;
  int lam = tid >> 2, lak = (tid & 3) * 4;
  int lbk = tid >> 4, lbn = (tid & 15) * 4;
  float acc[4][4] = {};
  int ar = m0 + lam;
  for (int k0 = 0; k0 < K; k0 += 16) {
    float4 av;
    if (ar < M) av = *(const float4*)(A + (size_t)ar * K + k0 + lak);
    else        av = make_float4(0.f, 0.f, 0.f, 0.f);
    As[lak + 0][lam] = av.x; As[lak + 1][lam] = av.y;
    As[lak + 2][lam] = av.z; As[lak + 3][lam] = av.w;
    *(float4*)&Bs[lbk][lbn] = *(const float4*)(B + (size_t)(k0 + lbk) * Nc + n0 + lbn);
    __syncthreads();
#pragma unroll
    for (int kk = 0; kk < 16; ++kk) {
      const float4 a4 = *(const float4*)&As[kk][ty << 2];
      const float4 b4 = *(const float4*)&Bs[kk][tx << 2];
      const float a[4] = {a4.x, a4.y, a4.z, a4.w};
      const float b[4] = {b4.x, b4.y, b4.z, b4.w};
#pragma unroll
      for (int i = 0; i < 4; ++i)
#pragma unroll
        for (int j = 0; j < 4; ++j)
          acc[i][j] = fmaf(a[i], b[j], acc[i][j]);
    }
    __syncthreads();
  }
#pragma unroll
  for (int i = 0; i < 4; ++i) {
    int row = m0 + ty * 4 + i;
    if (row >= M) continue;
#pragma unroll
    for (int j = 0; j < 4; ++j) {
      int col = n0 + tx * 4 + j;
      float v = acc[i][j] + bias[col];
      if (mode == 2) v = 0.5f * v * (1.0f + erff(v * 0.70710678118654752f));
      Cout[(size_t)row * Nc + col] = v;
    }
  }
}

// ---------------- attention score dots from fp16 xp: s_src/s_dst [N,4] ----------------
__global__ __launch_bounds__(256) void k_sdots(const __half* __restrict__ xp16,
                                               const float* __restrict__ asw,
                                               const float* __restrict__ adw,
                                               float* __restrict__ ssrc, float* __restrict__ sdst) {
  int wv = threadIdx.x >> 6, ln = threadIdx.x & 63;
  int n = blockIdx.x * 4 + wv;
  int h = ln >> 4, c0 = (ln & 15) * 8;
  uint4 raw = *(const uint4*)(xp16 + (size_t)n * DD + h * 128 + c0);
  const __half2* hp = (const __half2*)&raw;
  float a = 0.f, b = 0.f;
#pragma unroll
  for (int j = 0; j < 4; ++j) {
    float2 f = __half22float2(hp[j]);
    a += f.x * asw[h * 128 + c0 + 2 * j]     + f.y * asw[h * 128 + c0 + 2 * j + 1];
    b += f.x * adw[h * 128 + c0 + 2 * j]     + f.y * adw[h * 128 + c0 + 2 * j + 1];
  }
#pragma unroll
  for (int o = 8; o; o >>= 1) { a += __shfl_xor(a, o); b += __shfl_xor(b, o); }
  if ((ln & 15) == 0) { ssrc[n * 4 + h] = a; sdst[n * 4 + h] = b; }
}

// ---------------- per-edge softmax weights (max-subtracted) + per-node denoms ----------------
// wave per node; lanes strided over edges; w' = exp(e - m) in (0,1] stored fp16.
__global__ __launch_bounds__(256) void k_eweight(const float* __restrict__ ssrc,
                                                 const float* __restrict__ sdst,
                                                 const int* __restrict__ off,
                                                 const int* __restrict__ csr,
                                                 __half* __restrict__ ew,
                                                 float* __restrict__ den) {
  int wv = threadIdx.x >> 6, ln = threadIdx.x & 63;
  int n = blockIdx.x * 4 + wv;
  int beg = off[n], end = off[n + 1];
  float4 sd4 = *(const float4*)(sdst + (size_t)n * 4);
  float m0 = -1e30f, m1 = -1e30f, m2 = -1e30f, m3 = -1e30f;
  for (int k = beg + ln; k < end; k += 64) {
    float4 s = *(const float4*)(ssrc + (size_t)csr[k] * 4);
    float e0 = s.x + sd4.x; e0 = (e0 > 0.f) ? e0 : 0.2f * e0; m0 = fmaxf(m0, e0);
    float e1 = s.y + sd4.y; e1 = (e1 > 0.f) ? e1 : 0.2f * e1; m1 = fmaxf(m1, e1);
    float e2 = s.z + sd4.z; e2 = (e2 > 0.f) ? e2 : 0.2f * e2; m2 = fmaxf(m2, e2);
    float e3 = s.w + sd4.w; e3 = (e3 > 0.f) ? e3 : 0.2f * e3; m3 = fmaxf(m3, e3);
  }
#pragma unroll
  for (int o = 32; o; o >>= 1) {
    m0 = fmaxf(m0, __shfl_xor(m0, o));
    m1 = fmaxf(m1, __shfl_xor(m1, o));
    m2 = fmaxf(m2, __shfl_xor(m2, o));
    m3 = fmaxf(m3, __shfl_xor(m3, o));
  }
  float d0 = 0.f, d1 = 0.f, d2 = 0.f, d3 = 0.f;
  for (int k = beg + ln; k < end; k += 64) {
    float4 s = *(const float4*)(ssrc + (size_t)csr[k] * 4);
    float e0 = s.x + sd4.x; e0 = (e0 > 0.f) ? e0 : 0.2f * e0;
    float e1 = s.y + sd4.y; e1 = (e1 > 0.f) ? e1 : 0.2f * e1;
    float e2 = s.z + sd4.z; e2 = (e2 > 0.f) ? e2 : 0.2f * e2;
    float e3 = s.w + sd4.w; e3 = (e3 > 0.f) ? e3 : 0.2f * e3;
    __half2 p0 = __floats2half2_rn(__expf(e0 - m0), __expf(e1 - m1));
    __half2 p1 = __floats2half2_rn(__expf(e2 - m2), __expf(e3 - m3));
    float2 f0 = __half22float2(p0), f1 = __half22float2(p1);
    d0 += f0.x; d1 += f0.y; d2 += f1.x; d3 += f1.y;
    union { __half2 h; unsigned u; } c0, c1;
    c0.h = p0; c1.h = p1;
    uint2 st; st.x = c0.u; st.y = c1.u;
    *(uint2*)(ew + (size_t)k * 4) = st;
  }
#pragma unroll
  for (int o = 32; o; o >>= 1) {
    d0 += __shfl_xor(d0, o); d1 += __shfl_xor(d1, o);
    d2 += __shfl_xor(d2, o); d3 += __shfl_xor(d3, o);
  }
  if (ln == 0) *(float4*)(den + (size_t)n * 4) = make_float4(d0, d1, d2, d3);
}

// ---------------- channel-split aggregation: cb = blockIdx % 8 pins 64-ch slice to one XCD ----------------
// Each wave handles 2 nodes x 64 channels; per edge: 1 uniform w-load + one 128B L2-resident line.
__global__ __launch_bounds__(256, 8) void k_aggc(const __half* __restrict__ xp16,
                                                 const __half* __restrict__ ew,
                                                 const float* __restrict__ den,
                                                 const int* __restrict__ off,
                                                 const int* __restrict__ csr,
                                                 const float* __restrict__ bias,
                                                 float* __restrict__ xio,   // in: residual, out: pre-LN
                                                 float* __restrict__ psq) { // [NN][8][2]
  const int bid = blockIdx.x;
  const int cb = bid & 7;        // XCD-pinned channel block (HW round-robins blockIdx % 8)
  const int chunk = bid >> 3;    // node chunk of 8
  const int wv = threadIdx.x >> 6, ln = threadIdx.x & 63;
  const int c = cb * 64 + ln;
  const int h = cb >> 1;
  const float bi = bias[c];
#pragma unroll
  for (int t = 0; t < 2; ++t) {
    const int n = chunk * 8 + wv * 2 + t;
    const int beg = off[n], end = off[n + 1];
    float acc = 0.f;
    int k = beg;
    for (; k + 8 <= end; k += 8) {
      int sk[8];
#pragma unroll
      for (int u = 0; u < 8; ++u) sk[u] = csr[k + u];
      float x[8];
#pragma unroll
      for (int u = 0; u < 8; ++u) x[u] = __half2float(xp16[(size_t)sk[u] * DD + c]);
      float w[8];
#pragma unroll
      for (int u = 0; u < 8; ++u) w[u] = __half2float(ew[(size_t)(k + u) * 4 + h]);
#pragma unroll
      for (int u = 0; u < 8; ++u) acc = fmaf(w[u], x[u], acc);
    }
    for (; k < end; ++k) {
      float x = __half2float(xp16[(size_t)csr[k] * DD + c]);
      float w = __half2float(ew[(size_t)k * 4 + h]);
      acc = fmaf(w, x, acc);
    }
    float o = acc / den[(size_t)n * 4 + h] + bi + xio[(size_t)n * DD + c];
    xio[(size_t)n * DD + c] = o;
    float ps = o, pq = o * o;
#pragma unroll
    for (int oo = 32; oo; oo >>= 1) { ps += __shfl_xor(ps, oo); pq += __shfl_xor(pq, oo); }
    if (ln == 0) {
      psq[(size_t)n * 16 + cb * 2]     = ps;
      psq[(size_t)n * 16 + cb * 2 + 1] = pq;
    }
  }
}

// ---------------- per-graph LN stats from psq (batch sorted; binary search range) ----------------
__device__ __forceinline__ int lowb(const int* a, int n, int key) {
  int lo = 0, hi = n;
  while (lo < hi) { int mid = (lo + hi) >> 1; if (a[mid] < key) lo = mid + 1; else hi = mid; }
  return lo;
}

__global__ __launch_bounds__(256) void k_stats2(const float* __restrict__ psq,
                                                const int* __restrict__ batch,
                                                float* __restrict__ gmu, float* __restrict__ grstd) {
  int g = blockIdx.x, tid = threadIdx.x;
  __shared__ int sb, se;
  __shared__ float rs[4], rq[4];
  if (tid == 0) { sb = lowb(batch, NN, g); se = lowb(batch, NN, g + 1); }
  __syncthreads();
  int b = sb, e = se;
  float ps = 0.f, pq = 0.f;
  for (int n = b + tid; n < e; n += 256) {
    const float4* p = (const float4*)(psq + (size_t)n * 16);
#pragma unroll
    for (int i = 0; i < 4; ++i) {
      float4 v = p[i];
      ps += v.x + v.z;
      pq += v.y + v.w;
    }
  }
#pragma unroll
  for (int o = 32; o; o >>= 1) { ps += __shfl_xor(ps, o); pq += __shfl_xor(pq, o); }
  int wv = tid >> 6, ln = tid & 63;
  if (ln == 0) { rs[wv] = ps; rq[wv] = pq; }
  __syncthreads();
  if (tid == 0) {
    float S = rs[0] + rs[1] + rs[2] + rs[3];
    float Q = rq[0] + rq[1] + rq[2] + rq[3];
    float cnt = fmaxf((float)(e - b) * (float)DD, 1.0f);
    float mu  = S / cnt;
    float var = fmaxf(Q / cnt - mu * mu, 0.0f);
    gmu[g]   = mu;
    grstd[g] = rsqrtf(var + 1e-5f);
  }
}

// ---------------- graph-LN normalize + optional f16 write (next GEMM's A) ----------------
__global__ __launch_bounds__(256) void k_norm(float* __restrict__ x, const int* __restrict__ batch,
                                              const float* __restrict__ gmu, const float* __restrict__ grstd,
                                              const float* __restrict__ lnw, const float* __restrict__ lnb,
                                              __half* __restrict__ xh, int wf16) {
  for (int i4 = blockIdx.x * 256 + threadIdx.x; i4 < NN * DD / 4; i4 += gridDim.x * 256) {
    int i = i4 * 4;
    int n = i >> 9, d = i & 511;
    int g = batch[n];
    float mu = gmu[g], rs = grstd[g];
    float4 v = *(float4*)(x + i);
    float4 w = *(const float4*)(lnw + d);
    float4 b = *(const float4*)(lnb + d);
    v.x = (v.x - mu) * rs * w.x + b.x;
    v.y = (v.y - mu) * rs * w.y + b.y;
    v.z = (v.z - mu) * rs * w.z + b.z;
    v.w = (v.w - mu) * rs * w.w + b.w;
    *(float4*)(x + i) = v;
    if (wf16) {
      __half2* o = (__half2*)(xh + i);
      o[0] = __floats2half2_rn(v.x, v.y);
      o[1] = __floats2half2_rn(v.z, v.w);
    }
  }
}

// ---------------- pooling: mean + max per graph (batch_vec sorted) ----------------
__global__ __launch_bounds__(256) void k_pool(const float* __restrict__ x, const int* __restrict__ batch,
                                              float* __restrict__ pool) {
  int g = blockIdx.x, tid = threadIdx.x;
  __shared__ int sb, se;
  if (tid == 0) { sb = lowb(batch, NN, g); se = lowb(batch, NN, g + 1); }
  __syncthreads();
  int b = sb, e = se;
  float s0 = 0.f, s1 = 0.f, m0 = -INFINITY, m1 = -INFINITY;
  for (int n = b; n < e; ++n) {
    float v0 = x[(size_t)n * DD + tid];
    float v1 = x[(size_t)n * DD + tid + 256];
    s0 += v0; s1 += v1;
    m0 = fmaxf(m0, v0); m1 = fmaxf(m1, v1);
  }
  int cnt = e - b;
  float inv = 1.0f / (float)(cnt > 0 ? cnt : 1);
  pool[(size_t)g * 1024 + tid]             = s0 * inv;
  pool[(size_t)g * 1024 + tid + 256]       = s1 * inv;
  pool[(size_t)g * 1024 + 512 + tid]       = (cnt > 0) ? m0 : 0.f;
  pool[(size_t)g * 1024 + 512 + tid + 256] = (cnt > 0) ? m1 : 0.f;
}

// ---------------- final row L2 normalize ----------------
__global__ __launch_bounds__(256) void k_l2(float* __restrict__ h) {
  int g = blockIdx.x, t = threadIdx.x;
  float v = h[(size_t)g * OUTD + t];
  float q = v * v;
#pragma unroll
  for (int o = 32; o; o >>= 1) q += __shfl_xor(q, o);
  __shared__ float w[4];
  int wv = t >> 6, ln = t & 63;
  if (ln == 0) w[wv] = q;
  __syncthreads();
  float tot = w[0] + w[1] + w[2] + w[3];
  float nrm = fmaxf(sqrtf(tot), 1e-12f);
  h[(size_t)g * OUTD + t] = v / nrm;
}

// ---------------- launcher ----------------
extern "C" void kernel_launch(void* const* d_in, const int* in_sizes, int n_in,
                              void* d_out, int out_size, void* d_ws, size_t ws_size,
                              hipStream_t stream) {
  const int*   node_ids = (const int*)d_in[0];
  const int*   ei       = (const int*)d_in[1];
  const int*   batch    = (const int*)d_in[2];
  const float* emb      = (const float*)d_in[3];
  const float* W[4]  = {(const float*)d_in[4],  (const float*)d_in[10], (const float*)d_in[16], (const float*)d_in[22]};
  const float* AS[4] = {(const float*)d_in[5],  (const float*)d_in[11], (const float*)d_in[17], (const float*)d_in[23]};
  const float* AD[4] = {(const float*)d_in[6],  (const float*)d_in[12], (const float*)d_in[18], (const float*)d_in[24]};
  const float* BV[4] = {(const float*)d_in[7],  (const float*)d_in[13], (const float*)d_in[19], (const float*)d_in[25]};
  const float* LW[4] = {(const float*)d_in[8],  (const float*)d_in[14], (const float*)d_in[20], (const float*)d_in[26]};
  const float* LB[4] = {(const float*)d_in[9],  (const float*)d_in[15], (const float*)d_in[21], (const float*)d_in[27]};
  const float* res_w0 = (const float*)d_in[28];
  const float* p1w    = (const float*)d_in[29];
  const float* p1b    = (const float*)d_in[30];
  const float* p2w    = (const float*)d_in[31];
  const float* p2b    = (const float*)d_in[32];
  float* out = (float*)d_out;

  char* ws = (char*)d_ws;
  size_t pos = 0;
  auto alloc = [&](size_t bytes) -> char* {
    char* p = ws + pos;
    pos = (pos + bytes + 255) & ~size_t(255);
    return p;
  };
  float*  xb    = (float*)alloc((size_t)NN * DD * 4);
  __half* xh16  = (__half*)alloc((size_t)NN * DD * 2);   // also hosts x0 f16 [NN][64] early
  __half* xp16  = (__half*)alloc((size_t)NN * DD * 2);
  float*  ssrc  = (float*)alloc((size_t)NN * 4 * 4);
  float*  sdst  = (float*)alloc((size_t)NN * 4 * 4);
  int*    coff  = (int*)alloc((size_t)(NN + 1) * 4);
  int*    ccur  = (int*)alloc((size_t)NN * 4);
  int*    csrc  = (int*)alloc((size_t)ET * 4);
  __half* ew    = (__half*)alloc((size_t)ET * 4 * 2);
  float*  den   = (float*)alloc((size_t)NN * 4 * 4);
  float*  psq   = (float*)alloc((size_t)NN * 16 * 4);
  float*  gmu   = (float*)alloc((size_t)GG * 4 * 2);
  float*  grstd = gmu + GG;
  // transposed f16 hi/lo weights
  __half* w0th = (__half*)alloc((size_t)DEE * DD * 2); __half* w0tl = (__half*)alloc((size_t)DEE * DD * 2);
  __half* rwth = (__half*)alloc((size_t)DEE * DD * 2); __half* rwtl = (__half*)alloc((size_t)DEE * DD * 2);
  __half* wth[4] = {w0th, nullptr, nullptr, nullptr};
  __half* wtl[4] = {w0tl, nullptr, nullptr, nullptr};
  for (int i = 1; i < 4; ++i) {
    wth[i] = (__half*)alloc((size_t)DD * DD * 2);
    wtl[i] = (__half*)alloc((size_t)DD * DD * 2);
  }
  float* pool = (float*)alloc((size_t)GG * 1024 * 4);
  float* h1   = (float*)alloc((size_t)GG * 1024 * 4);
  (void)ws_size; (void)in_sizes; (void)n_in; (void)out_size;

  __half* x0f = xh16;   // [NN][64] f16, aliased (dead once L0 GEMMs finish)

  // ---- CSR + weight prep ----
  hipMemsetAsync(ccur, 0, (size_t)NN * 4, stream);
  k_embf16<<<1250, 256, 0, stream>>>(node_ids, emb, x0f);
  k_count<<<1024, 256, 0, stream>>>(ei, ccur);
  k_scan<<<1, 1024, 0, stream>>>(ccur, coff);
  hipMemsetAsync(ccur, 0, (size_t)NN * 4, stream);
  k_scatter<<<1024, 256, 0, stream>>>(ei, coff, ccur, csrc);
  k_wsplit16T<<<dim3(16, 2),  256, 0, stream>>>(W[0],   w0th, w0tl, DEE, DD);
  k_wsplit16T<<<dim3(16, 2),  256, 0, stream>>>(res_w0, rwth, rwtl, DEE, DD);
  for (int i = 1; i < 4; ++i)
    k_wsplit16T<<<dim3(16, 16), 256, 0, stream>>>(W[i], wth[i], wtl[i], DD, DD);

  // ---- L0 projections ----
  k_mfma2<1><<<dim3(4, 157), 256, 0, stream>>>(x0f, w0th, w0tl, xp16, NN, DEE);
  k_mfma2<0><<<dim3(4, 157), 256, 0, stream>>>(x0f, rwth, rwtl, xb,   NN, DEE);

  // ---- 4 GAT layers ----
  for (int L = 0; L < 4; ++L) {
    k_sdots<<<NN / 4, 256, 0, stream>>>(xp16, AS[L], AD[L], ssrc, sdst);
    k_eweight<<<NN / 4, 256, 0, stream>>>(ssrc, sdst, coff, csrc, ew, den);
    k_aggc<<<NN, 256, 0, stream>>>(xp16, ew, den, coff, csrc, BV[L], xb, psq);
    k_stats2<<<GG, 256, 0, stream>>>(psq, batch, gmu, grstd);
    k_norm<<<2048, 256, 0, stream>>>(xb, batch, gmu, grstd, LW[L], LB[L], xh16, (L < 3) ? 1 : 0);
    if (L < 3)
      k_mfma2<1><<<dim3(4, 157), 256, 0, stream>>>(xh16, wth[L + 1], wtl[L + 1], xp16, NN, DD);
  }

  // ---- pool + MLP head + normalize ----
  k_pool<<<GG, 256, 0, stream>>>(xb, batch, pool);
  k_gemm<<<dim3(2, 16), 256, 0, stream>>>(pool, p1w, h1, p1b, GG, 1024, 1024, 2);
  k_gemm<<<dim3(2, 4), 256, 0, stream>>>(h1, p2w, out, p2b, GG, OUTD, 1024, 1);
  k_l2<<<GG, 256, 0, stream>>>(out);
}

// Round 7
// 839.487 us; speedup vs baseline: 1.2968x; 1.1338x over previous
//
#include <hip/hip_runtime.h>
#include <hip/hip_fp16.h>
#include <math.h>

constexpr int NN   = 20000;
constexpr int EE   = 320000;
constexpr int ET   = EE + NN;   // 340000 with self loops
constexpr int GG   = 128;
constexpr int DEE  = 64;
constexpr int DD   = 512;
constexpr int OUTD = 256;

using half8 = __attribute__((ext_vector_type(8))) _Float16;
using f32x4 = __attribute__((ext_vector_type(4))) float;

// ---- async global->LDS 16B (wave-uniform LDS base + lane*16 implicit) ----
__device__ __forceinline__ void ldg2lds16(const void* g, void* l) {
  __builtin_amdgcn_global_load_lds((const __attribute__((address_space(1))) unsigned*)g,
                                   (__attribute__((address_space(3))) unsigned*)l, 16, 0, 0);
}

// ---------------- embedding gather -> f16 ----------------
__global__ __launch_bounds__(256) void k_embf16(const int* __restrict__ ids,
                                                const float* __restrict__ emb,
                                                __half* __restrict__ x0) {
  for (int i = blockIdx.x * 256 + threadIdx.x; i < NN * 16; i += gridDim.x * 256) {
    int n = i >> 4, q = (i & 15) * 4;
    float4 v = *(const float4*)(emb + (size_t)ids[n] * DEE + q);
    __half2* o = (__half2*)(x0 + (size_t)n * DEE + q);
    o[0] = __floats2half2_rn(v.x, v.y);
    o[1] = __floats2half2_rn(v.z, v.w);
  }
}

// ---------------- weight transpose + f16 hi/lo split: T[n][k] = W[k][n] ----------------
__global__ __launch_bounds__(256) void k_wsplit16T(const float* __restrict__ W,
                                                   __half* __restrict__ Th, __half* __restrict__ Tl,
                                                   int K, int N) {
  __shared__ float t[32][33];
  int n0 = blockIdx.x * 32, k0 = blockIdx.y * 32;
  int c = threadIdx.x & 31, r4 = threadIdx.x >> 5;
  for (int rr = 0; rr < 32; rr += 8)
    t[rr + r4][c] = W[(size_t)(k0 + rr + r4) * N + n0 + c];
  __syncthreads();
  for (int rr = 0; rr < 32; rr += 8) {
    int n = n0 + rr + r4, k = k0 + c;
    float v = t[c][rr + r4];
    __half hi = __float2half_rn(v);
    Th[(size_t)n * K + k] = hi;
    Tl[(size_t)n * K + k] = __float2half_rn(v - __half2float(hi));
  }
}

// ---------------- CSR build ----------------
__global__ __launch_bounds__(256) void k_count(const int* __restrict__ ei, int* __restrict__ cnt) {
  for (int k = blockIdx.x * 256 + threadIdx.x; k < ET; k += gridDim.x * 256) {
    int d = (k < EE) ? ei[EE + k] : (k - EE);
    atomicAdd(&cnt[d], 1);
  }
}

__global__ __launch_bounds__(1024) void k_scan(const int* __restrict__ cnt, int* __restrict__ off) {
  __shared__ int part[1024];
  int tid = threadIdx.x;
  constexpr int CH = (NN + 1023) / 1024;  // 20
  int base = tid * CH;
  int s = 0;
  for (int i = 0; i < CH; ++i) { int idx = base + i; if (idx < NN) s += cnt[idx]; }
  part[tid] = s;
  __syncthreads();
  for (int o = 1; o < 1024; o <<= 1) {
    int add = (tid >= o) ? part[tid - o] : 0;
    int v = part[tid];
    __syncthreads();
    part[tid] = v + add;
    __syncthreads();
  }
  int run = (tid == 0) ? 0 : part[tid - 1];
  for (int i = 0; i < CH; ++i) {
    int idx = base + i;
    if (idx < NN) { off[idx] = run; run += cnt[idx]; }
  }
  if (tid == 1023) off[NN] = ET;
}

__global__ __launch_bounds__(256) void k_scatter(const int* __restrict__ ei, const int* __restrict__ off,
                                                 int* __restrict__ cur, int* __restrict__ csrc) {
  for (int k = blockIdx.x * 256 + threadIdx.x; k < ET; k += gridDim.x * 256) {
    int s = (k < EE) ? ei[k]      : (k - EE);
    int d = (k < EE) ? ei[EE + k] : (k - EE);
    int p = atomicAdd(&cur[d], 1);
    csrc[off[d] + p] = s;
  }
}

// ---------------- f16 MFMA GEMM (A single + B hi/lo split): C[M,512] = A[M,K] @ B ----------------
template<int OUT16>
__global__ __launch_bounds__(256) void k_mfma2(const __half* __restrict__ A,
                                               const __half* __restrict__ Bh,
                                               const __half* __restrict__ Bl,
                                               void* __restrict__ Cout, int M, int K) {
  __shared__ __half lds[3 * 128 * 64];   // A | Bh | Bl, 16 KB each
  __half* As  = lds;
  __half* Bhs = lds + 8192;
  __half* Bls = lds + 16384;
  const int tid = threadIdx.x, l = tid & 63, w = tid >> 6;
  const int wr = w >> 1, wc = w & 1;
  const int m0 = blockIdx.y * 128, n0 = blockIdx.x * 128;
  const int l15 = l & 15, l16 = l >> 4;
  const int sr = l >> 3;                 // staging sub-row 0..7
  const int ss = (l & 7) ^ sr;           // staging swizzled 16B slot

  f32x4 acc[4][4] = {};
  for (int k0 = 0; k0 < K; k0 += 64) {
#pragma unroll
    for (int j = 0; j < 4; ++j) {
      int rbase = j * 32 + w * 8;
      int rl = rbase + sr;
      int gA = min(m0 + rl, M - 1);
      int gB = n0 + rl;
      const size_t ko = (size_t)(k0 + ss * 8);
      ldg2lds16(A  + (size_t)gA * K + ko, As  + rbase * 64);
      ldg2lds16(Bh + (size_t)gB * K + ko, Bhs + rbase * 64);
      ldg2lds16(Bl + (size_t)gB * K + ko, Bls + rbase * 64);
    }
    __syncthreads();
#pragma unroll
    for (int kh = 0; kh < 2; ++kh) {
      half8 af[4], bhf[4], blf[4];
#pragma unroll
      for (int t = 0; t < 4; ++t) {
        int ra = wr * 64 + t * 16 + l15;
        int ca = (kh * 4 + l16) ^ (ra & 7);
        af[t] = *(const half8*)(As + ra * 64 + ca * 8);
        int rb = wc * 64 + t * 16 + l15;
        int cb = (kh * 4 + l16) ^ (rb & 7);
        bhf[t] = *(const half8*)(Bhs + rb * 64 + cb * 8);
        blf[t] = *(const half8*)(Bls + rb * 64 + cb * 8);
      }
#pragma unroll
      for (int i = 0; i < 4; ++i)
#pragma unroll
        for (int j = 0; j < 4; ++j) {
          acc[i][j] = __builtin_amdgcn_mfma_f32_16x16x32_f16(af[i], bhf[j], acc[i][j], 0, 0, 0);
          acc[i][j] = __builtin_amdgcn_mfma_f32_16x16x32_f16(af[i], blf[j], acc[i][j], 0, 0, 0);
        }
    }
    __syncthreads();
  }
#pragma unroll
  for (int i = 0; i < 4; ++i) {
#pragma unroll
    for (int r = 0; r < 4; ++r) {
      int row = m0 + wr * 64 + i * 16 + l16 * 4 + r;
      if (row >= M) continue;
#pragma unroll
      for (int j = 0; j < 4; ++j) {
        int col = n0 + wc * 64 + j * 16 + l15;
        float v = acc[i][j][r];
        if (OUT16) ((__half*)Cout)[(size_t)row * DD + col] = __float2half(v);
        else       ((float*)Cout)[(size_t)row * DD + col]  = v;
      }
    }
  }
}

// ---------------- fp32 tiled GEMM 64x64 (MLP head) ----------------
// mode: 1 = +bias, 2 = +bias then exact GELU
__global__ __launch_bounds__(256) void k_gemm(const float* __restrict__ A, const float* __restrict__ B,
                                              float* __restrict__ Cout, const float* __restrict__ bias,
                                              int M, int Nc, int K, int mode) {
  __shared__ float As[16][68];
  __shared__ float Bs[16][68];
  int tid = threadIdx.x;
  int m0 = blockIdx.x * 64, n0 = blockIdx.y * 64;
  int tx = tid & 15, ty = tid >> 4;
  int lam = tid >> 2, lak = (tid & 3) * 4;
  int lbk = tid >> 4, lbn = (tid & 15) * 4;
  float acc[4][4] = {};
  int ar = m0 + lam;
  for (int k0 = 0; k0 < K; k0 += 16) {
    float4 av;
    if (ar < M) av = *(const float4*)(A + (size_t)ar * K + k0 + lak);
    else        av = make_float4(0.f, 0.f, 0.f, 0.f);
    As[lak + 0][lam] = av.x; As[lak + 1][lam] = av.y;
    As[lak + 2][lam] = av.z; As[lak + 3][lam] = av.w;
    *(float4*)&Bs[lbk][lbn] = *(const float4*)(B + (size_t)(k0 + lbk) * Nc + n0 + lbn);
    __syncthreads();
#pragma unroll
    for (int kk = 0; kk < 16; ++kk) {
      const float4 a4 = *(const float4*)&As[kk][ty << 2];
      const float4 b4 = *(const float4*)&Bs[kk][tx << 2];
      const float a[4] = {a4.x, a4.y, a4.z, a4.w};
      const float b[4] = {b4.x, b4.y, b4.z, b4.w};
#pragma unroll
      for (int i = 0; i < 4; ++i)
#pragma unroll
        for (int j = 0; j < 4; ++j)
          acc[i][j] = fmaf(a[i], b[j], acc[i][j]);
    }
    __syncthreads();
  }
#pragma unroll
  for (int i = 0; i < 4; ++i) {
    int row = m0 + ty * 4 + i;
    if (row >= M) continue;
#pragma unroll
    for (int j = 0; j < 4; ++j) {
      int col = n0 + tx * 4 + j;
      float v = acc[i][j] + bias[col];
      if (mode == 2) v = 0.5f * v * (1.0f + erff(v * 0.70710678118654752f));
      Cout[(size_t)row * Nc + col] = v;
    }
  }
}

// ---------------- attention score dots from fp16 xp: s_src/s_dst [N,4] ----------------
__global__ __launch_bounds__(256) void k_sdots(const __half* __restrict__ xp16,
                                               const float* __restrict__ asw,
                                               const float* __restrict__ adw,
                                               float* __restrict__ ssrc, float* __restrict__ sdst) {
  int wv = threadIdx.x >> 6, ln = threadIdx.x & 63;
  int n = blockIdx.x * 4 + wv;
  int h = ln >> 4, c0 = (ln & 15) * 8;
  uint4 raw = *(const uint4*)(xp16 + (size_t)n * DD + h * 128 + c0);
  const __half2* hp = (const __half2*)&raw;
  float a = 0.f, b = 0.f;
#pragma unroll
  for (int j = 0; j < 4; ++j) {
    float2 f = __half22float2(hp[j]);
    a += f.x * asw[h * 128 + c0 + 2 * j]     + f.y * asw[h * 128 + c0 + 2 * j + 1];
    b += f.x * adw[h * 128 + c0 + 2 * j]     + f.y * adw[h * 128 + c0 + 2 * j + 1];
  }
#pragma unroll
  for (int o = 8; o; o >>= 1) { a += __shfl_xor(a, o); b += __shfl_xor(b, o); }
  if ((ln & 15) == 0) { ssrc[n * 4 + h] = a; sdst[n * 4 + h] = b; }
}

// ---------------- per-edge softmax weights (max-subtracted) into f32 SoA planes ----------------
// wave per node; lanes strided over edges; plane h: ewp[h*ET + k] (coalesced per plane).
__global__ __launch_bounds__(256) void k_eweight(const float* __restrict__ ssrc,
                                                 const float* __restrict__ sdst,
                                                 const int* __restrict__ off,
                                                 const int* __restrict__ csr,
                                                 float* __restrict__ ewp,
                                                 float* __restrict__ den) {
  int wv = threadIdx.x >> 6, ln = threadIdx.x & 63;
  int n = blockIdx.x * 4 + wv;
  int beg = off[n], end = off[n + 1];
  float4 sd4 = *(const float4*)(sdst + (size_t)n * 4);
  float m0 = -1e30f, m1 = -1e30f, m2 = -1e30f, m3 = -1e30f;
  for (int k = beg + ln; k < end; k += 64) {
    float4 s = *(const float4*)(ssrc + (size_t)csr[k] * 4);
    float e0 = s.x + sd4.x; e0 = (e0 > 0.f) ? e0 : 0.2f * e0; m0 = fmaxf(m0, e0);
    float e1 = s.y + sd4.y; e1 = (e1 > 0.f) ? e1 : 0.2f * e1; m1 = fmaxf(m1, e1);
    float e2 = s.z + sd4.z; e2 = (e2 > 0.f) ? e2 : 0.2f * e2; m2 = fmaxf(m2, e2);
    float e3 = s.w + sd4.w; e3 = (e3 > 0.f) ? e3 : 0.2f * e3; m3 = fmaxf(m3, e3);
  }
#pragma unroll
  for (int o = 32; o; o >>= 1) {
    m0 = fmaxf(m0, __shfl_xor(m0, o));
    m1 = fmaxf(m1, __shfl_xor(m1, o));
    m2 = fmaxf(m2, __shfl_xor(m2, o));
    m3 = fmaxf(m3, __shfl_xor(m3, o));
  }
  float d0 = 0.f, d1 = 0.f, d2 = 0.f, d3 = 0.f;
  for (int k = beg + ln; k < end; k += 64) {
    float4 s = *(const float4*)(ssrc + (size_t)csr[k] * 4);
    float e0 = s.x + sd4.x; e0 = (e0 > 0.f) ? e0 : 0.2f * e0;
    float e1 = s.y + sd4.y; e1 = (e1 > 0.f) ? e1 : 0.2f * e1;
    float e2 = s.z + sd4.z; e2 = (e2 > 0.f) ? e2 : 0.2f * e2;
    float e3 = s.w + sd4.w; e3 = (e3 > 0.f) ? e3 : 0.2f * e3;
    float w0 = __expf(e0 - m0), w1 = __expf(e1 - m1);
    float w2 = __expf(e2 - m2), w3 = __expf(e3 - m3);
    d0 += w0; d1 += w1; d2 += w2; d3 += w3;
    ewp[k]          = w0;
    ewp[ET + k]     = w1;
    ewp[2 * ET + k] = w2;
    ewp[3 * ET + k] = w3;
  }
#pragma unroll
  for (int o = 32; o; o >>= 1) {
    d0 += __shfl_xor(d0, o); d1 += __shfl_xor(d1, o);
    d2 += __shfl_xor(d2, o); d3 += __shfl_xor(d3, o);
  }
  if (ln == 0) *(float4*)(den + (size_t)n * 4) = make_float4(d0, d1, d2, d3);
}

// ---------------- channel-split aggregation (XCD-pinned slice, scalarized edge stream) ----------------
// cb = blockIdx % 8 pins a 64-channel slice (2.56 MB of xp16) to one XCD's L2.
// readfirstlane makes n/beg/end/csr/ew provably wave-uniform -> scalar s_loads, ~3 VALU/edge.
__global__ __launch_bounds__(256, 8) void k_aggc(const __half* __restrict__ xp16,
                                                 const float* __restrict__ ewp,
                                                 const float* __restrict__ den,
                                                 const int* __restrict__ off,
                                                 const int* __restrict__ csr,
                                                 const float* __restrict__ bias,
                                                 float* __restrict__ xio,   // in: residual, out: pre-LN
                                                 float* __restrict__ psq) { // [NN][8][2]
  const int bid = blockIdx.x;
  const int cb = bid & 7;        // XCD-pinned channel block (HW round-robins blockIdx % 8)
  const int chunk = bid >> 3;    // node chunk of 8
  const int wv = threadIdx.x >> 6, ln = threadIdx.x & 63;
  const int c = cb * 64 + ln;
  const int h = cb >> 1;
  const float bi = bias[c];
  const float* __restrict__ ewh = ewp + (size_t)h * ET;
#pragma unroll
  for (int t = 0; t < 2; ++t) {
    const int n = __builtin_amdgcn_readfirstlane(chunk * 8 + wv * 2 + t);
    const int beg = off[n], end = off[n + 1];
    float acc = 0.f;
    int k = beg;
    for (; k + 8 <= end; k += 8) {
      int sk[8];
#pragma unroll
      for (int u = 0; u < 8; ++u) sk[u] = csr[k + u];          // scalar s_load
      float w[8];
#pragma unroll
      for (int u = 0; u < 8; ++u) w[u] = ewh[k + u];           // scalar s_load
      float x[8];
#pragma unroll
      for (int u = 0; u < 8; ++u) x[u] = __half2float(xp16[(size_t)sk[u] * DD + c]);
#pragma unroll
      for (int u = 0; u < 8; ++u) acc = fmaf(w[u], x[u], acc);
    }
    for (; k < end; ++k) {
      float x = __half2float(xp16[(size_t)csr[k] * DD + c]);
      acc = fmaf(ewh[k], x, acc);
    }
    float o = acc / den[(size_t)n * 4 + h] + bi + xio[(size_t)n * DD + c];
    xio[(size_t)n * DD + c] = o;
    float ps = o, pq = o * o;
#pragma unroll
    for (int oo = 32; oo; oo >>= 1) { ps += __shfl_xor(ps, oo); pq += __shfl_xor(pq, oo); }
    if (ln == 0) {
      psq[(size_t)n * 16 + cb * 2]     = ps;
      psq[(size_t)n * 16 + cb * 2 + 1] = pq;
    }
  }
}

// ---------------- per-graph LN stats from psq (batch sorted; binary search range) ----------------
__device__ __forceinline__ int lowb(const int* a, int n, int key) {
  int lo = 0, hi = n;
  while (lo < hi) { int mid = (lo + hi) >> 1; if (a[mid] < key) lo = mid + 1; else hi = mid; }
  return lo;
}

__global__ __launch_bounds__(256) void k_stats2(const float* __restrict__ psq,
                                                const int* __restrict__ batch,
                                                float* __restrict__ gmu, float* __restrict__ grstd) {
  int g = blockIdx.x, tid = threadIdx.x;
  __shared__ int sb, se;
  __shared__ float rs[4], rq[4];
  if (tid == 0) { sb = lowb(batch, NN, g); se = lowb(batch, NN, g + 1); }
  __syncthreads();
  int b = sb, e = se;
  float ps = 0.f, pq = 0.f;
  for (int n = b + tid; n < e; n += 256) {
    const float4* p = (const float4*)(psq + (size_t)n * 16);
#pragma unroll
    for (int i = 0; i < 4; ++i) {
      float4 v = p[i];
      ps += v.x + v.z;
      pq += v.y + v.w;
    }
  }
#pragma unroll
  for (int o = 32; o; o >>= 1) { ps += __shfl_xor(ps, o); pq += __shfl_xor(pq, o); }
  int wv = tid >> 6, ln = tid & 63;
  if (ln == 0) { rs[wv] = ps; rq[wv] = pq; }
  __syncthreads();
  if (tid == 0) {
    float S = rs[0] + rs[1] + rs[2] + rs[3];
    float Q = rq[0] + rq[1] + rq[2] + rq[3];
    float cnt = fmaxf((float)(e - b) * (float)DD, 1.0f);
    float mu  = S / cnt;
    float var = fmaxf(Q / cnt - mu * mu, 0.0f);
    gmu[g]   = mu;
    grstd[g] = rsqrtf(var + 1e-5f);
  }
}

// ---------------- graph-LN normalize + optional f16 write (next GEMM's A) ----------------
__global__ __launch_bounds__(256) void k_norm(float* __restrict__ x, const int* __restrict__ batch,
                                              const float* __restrict__ gmu, const float* __restrict__ grstd,
                                              const float* __restrict__ lnw, const float* __restrict__ lnb,
                                              __half* __restrict__ xh, int wf16) {
  for (int i4 = blockIdx.x * 256 + threadIdx.x; i4 < NN * DD / 4; i4 += gridDim.x * 256) {
    int i = i4 * 4;
    int n = i >> 9, d = i & 511;
    int g = batch[n];
    float mu = gmu[g], rs = grstd[g];
    float4 v = *(float4*)(x + i);
    float4 w = *(const float4*)(lnw + d);
    float4 b = *(const float4*)(lnb + d);
    v.x = (v.x - mu) * rs * w.x + b.x;
    v.y = (v.y - mu) * rs * w.y + b.y;
    v.z = (v.z - mu) * rs * w.z + b.z;
    v.w = (v.w - mu) * rs * w.w + b.w;
    *(float4*)(x + i) = v;
    if (wf16) {
      __half2* o = (__half2*)(xh + i);
      o[0] = __floats2half2_rn(v.x, v.y);
      o[1] = __floats2half2_rn(v.z, v.w);
    }
  }
}

// ---------------- pooling: mean + max per graph (batch_vec sorted) ----------------
__global__ __launch_bounds__(256) void k_pool(const float* __restrict__ x, const int* __restrict__ batch,
                                              float* __restrict__ pool) {
  int g = blockIdx.x, tid = threadIdx.x;
  __shared__ int sb, se;
  if (tid == 0) { sb = lowb(batch, NN, g); se = lowb(batch, NN, g + 1); }
  __syncthreads();
  int b = sb, e = se;
  float s0 = 0.f, s1 = 0.f, m0 = -INFINITY, m1 = -INFINITY;
  for (int n = b; n < e; ++n) {
    float v0 = x[(size_t)n * DD + tid];
    float v1 = x[(size_t)n * DD + tid + 256];
    s0 += v0; s1 += v1;
    m0 = fmaxf(m0, v0); m1 = fmaxf(m1, v1);
  }
  int cnt = e - b;
  float inv = 1.0f / (float)(cnt > 0 ? cnt : 1);
  pool[(size_t)g * 1024 + tid]             = s0 * inv;
  pool[(size_t)g * 1024 + tid + 256]       = s1 * inv;
  pool[(size_t)g * 1024 + 512 + tid]       = (cnt > 0) ? m0 : 0.f;
  pool[(size_t)g * 1024 + 512 + tid + 256] = (cnt > 0) ? m1 : 0.f;
}

// ---------------- final row L2 normalize ----------------
__global__ __launch_bounds__(256) void k_l2(float* __restrict__ h) {
  int g = blockIdx.x, t = threadIdx.x;
  float v = h[(size_t)g * OUTD + t];
  float q = v * v;
#pragma unroll
  for (int o = 32; o; o >>= 1) q += __shfl_xor(q, o);
  __shared__ float w[4];
  int wv = t >> 6, ln = t & 63;
  if (ln == 0) w[wv] = q;
  __syncthreads();
  float tot = w[0] + w[1] + w[2] + w[3];
  float nrm = fmaxf(sqrtf(tot), 1e-12f);
  h[(size_t)g * OUTD + t] = v / nrm;
}

// ---------------- launcher ----------------
extern "C" void kernel_launch(void* const* d_in, const int* in_sizes, int n_in,
                              void* d_out, int out_size, void* d_ws, size_t ws_size,
                              hipStream_t stream) {
  const int*   node_ids = (const int*)d_in[0];
  const int*   ei       = (const int*)d_in[1];
  const int*   batch    = (const int*)d_in[2];
  const float* emb      = (const float*)d_in[3];
  const float* W[4]  = {(const float*)d_in[4],  (const float*)d_in[10], (const float*)d_in[16], (const float*)d_in[22]};
  const float* AS[4] = {(const float*)d_in[5],  (const float*)d_in[11], (const float*)d_in[17], (const float*)d_in[23]};
  const float* AD[4] = {(const float*)d_in[6],  (const float*)d_in[12], (const float*)d_in[18], (const float*)d_in[24]};
  const float* BV[4] = {(const float*)d_in[7],  (const float*)d_in[13], (const float*)d_in[19], (const float*)d_in[25]};
  const float* LW[4] = {(const float*)d_in[8],  (const float*)d_in[14], (const float*)d_in[20], (const float*)d_in[26]};
  const float* LB[4] = {(const float*)d_in[9],  (const float*)d_in[15], (const float*)d_in[21], (const float*)d_in[27]};
  const float* res_w0 = (const float*)d_in[28];
  const float* p1w    = (const float*)d_in[29];
  const float* p1b    = (const float*)d_in[30];
  const float* p2w    = (const float*)d_in[31];
  const float* p2b    = (const float*)d_in[32];
  float* out = (float*)d_out;

  char* ws = (char*)d_ws;
  size_t pos = 0;
  auto alloc = [&](size_t bytes) -> char* {
    char* p = ws + pos;
    pos = (pos + bytes + 255) & ~size_t(255);
    return p;
  };
  float*  xb    = (float*)alloc((size_t)NN * DD * 4);
  __half* xh16  = (__half*)alloc((size_t)NN * DD * 2);   // also hosts x0 f16 [NN][64] early
  __half* xp16  = (__half*)alloc((size_t)NN * DD * 2);
  float*  ssrc  = (float*)alloc((size_t)NN * 4 * 4);
  float*  sdst  = (float*)alloc((size_t)NN * 4 * 4);
  int*    coff  = (int*)alloc((size_t)(NN + 1) * 4);
  int*    ccur  = (int*)alloc((size_t)NN * 4);
  int*    csrc  = (int*)alloc((size_t)ET * 4);
  float*  ewp   = (float*)alloc((size_t)ET * 4 * 4);     // 4 head planes, f32
  float*  den   = (float*)alloc((size_t)NN * 4 * 4);
  float*  psq   = (float*)alloc((size_t)NN * 16 * 4);
  float*  gmu   = (float*)alloc((size_t)GG * 4 * 2);
  float*  grstd = gmu + GG;
  // transposed f16 hi/lo weights
  __half* w0th = (__half*)alloc((size_t)DEE * DD * 2); __half* w0tl = (__half*)alloc((size_t)DEE * DD * 2);
  __half* rwth = (__half*)alloc((size_t)DEE * DD * 2); __half* rwtl = (__half*)alloc((size_t)DEE * DD * 2);
  __half* wth[4] = {w0th, nullptr, nullptr, nullptr};
  __half* wtl[4] = {w0tl, nullptr, nullptr, nullptr};
  for (int i = 1; i < 4; ++i) {
    wth[i] = (__half*)alloc((size_t)DD * DD * 2);
    wtl[i] = (__half*)alloc((size_t)DD * DD * 2);
  }
  float* pool = (float*)alloc((size_t)GG * 1024 * 4);
  float* h1   = (float*)alloc((size_t)GG * 1024 * 4);
  (void)ws_size; (void)in_sizes; (void)n_in; (void)out_size;

  __half* x0f = xh16;   // [NN][64] f16, aliased (dead once L0 GEMMs finish)

  // ---- CSR + weight prep ----
  hipMemsetAsync(ccur, 0, (size_t)NN * 4, stream);
  k_embf16<<<1250, 256, 0, stream>>>(node_ids, emb, x0f);
  k_count<<<1024, 256, 0, stream>>>(ei, ccur);
  k_scan<<<1, 1024, 0, stream>>>(ccur, coff);
  hipMemsetAsync(ccur, 0, (size_t)NN * 4, stream);
  k_scatter<<<1024, 256, 0, stream>>>(ei, coff, ccur, csrc);
  k_wsplit16T<<<dim3(16, 2),  256, 0, stream>>>(W[0],   w0th, w0tl, DEE, DD);
  k_wsplit16T<<<dim3(16, 2),  256, 0, stream>>>(res_w0, rwth, rwtl, DEE, DD);
  for (int i = 1; i < 4; ++i)
    k_wsplit16T<<<dim3(16, 16), 256, 0, stream>>>(W[i], wth[i], wtl[i], DD, DD);

  // ---- L0 projections ----
  k_mfma2<1><<<dim3(4, 157), 256, 0, stream>>>(x0f, w0th, w0tl, xp16, NN, DEE);
  k_mfma2<0><<<dim3(4, 157), 256, 0, stream>>>(x0f, rwth, rwtl, xb,   NN, DEE);

  // ---- 4 GAT layers ----
  for (int L = 0; L < 4; ++L) {
    k_sdots<<<NN / 4, 256, 0, stream>>>(xp16, AS[L], AD[L], ssrc, sdst);
    k_eweight<<<NN / 4, 256, 0, stream>>>(ssrc, sdst, coff, csrc, ewp, den);
    k_aggc<<<NN, 256, 0, stream>>>(xp16, ewp, den, coff, csrc, BV[L], xb, psq);
    k_stats2<<<GG, 256, 0, stream>>>(psq, batch, gmu, grstd);
    k_norm<<<2048, 256, 0, stream>>>(xb, batch, gmu, grstd, LW[L], LB[L], xh16, (L < 3) ? 1 : 0);
    if (L < 3)
      k_mfma2<1><<<dim3(4, 157), 256, 0, stream>>>(xh16, wth[L + 1], wtl[L + 1], xp16, NN, DD);
  }

  // ---- pool + MLP head + normalize ----
  k_pool<<<GG, 256, 0, stream>>>(xb, batch, pool);
  k_gemm<<<dim3(2, 16), 256, 0, stream>>>(pool, p1w, h1, p1b, GG, 1024, 1024, 2);
  k_gemm<<<dim3(2, 4), 256, 0, stream>>>(h1, p2w, out, p2b, GG, OUTD, 1024, 1);
  k_l2<<<GG, 256, 0, stream>>>(out);
}

// Round 8
// 760.326 us; speedup vs baseline: 1.4318x; 1.1041x over previous
//
#include <hip/hip_runtime.h>
#include <hip/hip_fp16.h>
#include <math.h>

constexpr int NN   = 20000;
constexpr int EE   = 320000;
constexpr int ET   = EE + NN;   // 340000 with self loops
constexpr int GG   = 128;
constexpr int DEE  = 64;
constexpr int DD   = 512;
constexpr int OUTD = 256;

using half8 = __attribute__((ext_vector_type(8))) _Float16;
using f32x4 = __attribute__((ext_vector_type(4))) float;

// ---- async global->LDS 16B (wave-uniform LDS base + lane*16 implicit) ----
__device__ __forceinline__ void ldg2lds16(const void* g, void* l) {
  __builtin_amdgcn_global_load_lds((const __attribute__((address_space(1))) unsigned*)g,
                                   (__attribute__((address_space(3))) unsigned*)l, 16, 0, 0);
}

// ---------------- embedding gather -> f16 ----------------
__global__ __launch_bounds__(256) void k_embf16(const int* __restrict__ ids,
                                                const float* __restrict__ emb,
                                                __half* __restrict__ x0) {
  for (int i = blockIdx.x * 256 + threadIdx.x; i < NN * 16; i += gridDim.x * 256) {
    int n = i >> 4, q = (i & 15) * 4;
    float4 v = *(const float4*)(emb + (size_t)ids[n] * DEE + q);
    __half2* o = (__half2*)(x0 + (size_t)n * DEE + q);
    o[0] = __floats2half2_rn(v.x, v.y);
    o[1] = __floats2half2_rn(v.z, v.w);
  }
}

// ---------------- weight transpose + f16 hi/lo split: T[n][k] = W[k][n] ----------------
__global__ __launch_bounds__(256) void k_wsplit16T(const float* __restrict__ W,
                                                   __half* __restrict__ Th, __half* __restrict__ Tl,
                                                   int K, int N) {
  __shared__ float t[32][33];
  int n0 = blockIdx.x * 32, k0 = blockIdx.y * 32;
  int c = threadIdx.x & 31, r4 = threadIdx.x >> 5;
  for (int rr = 0; rr < 32; rr += 8)
    t[rr + r4][c] = W[(size_t)(k0 + rr + r4) * N + n0 + c];
  __syncthreads();
  for (int rr = 0; rr < 32; rr += 8) {
    int n = n0 + rr + r4, k = k0 + c;
    float v = t[c][rr + r4];
    __half hi = __float2half_rn(v);
    Th[(size_t)n * K + k] = hi;
    Tl[(size_t)n * K + k] = __float2half_rn(v - __half2float(hi));
  }
}

// ---------------- CSR build ----------------
__global__ __launch_bounds__(256) void k_count(const int* __restrict__ ei, int* __restrict__ cnt) {
  for (int k = blockIdx.x * 256 + threadIdx.x; k < ET; k += gridDim.x * 256) {
    int d = (k < EE) ? ei[EE + k] : (k - EE);
    atomicAdd(&cnt[d], 1);
  }
}

__global__ __launch_bounds__(1024) void k_scan(const int* __restrict__ cnt, int* __restrict__ off) {
  __shared__ int part[1024];
  int tid = threadIdx.x;
  constexpr int CH = (NN + 1023) / 1024;  // 20
  int base = tid * CH;
  int s = 0;
  for (int i = 0; i < CH; ++i) { int idx = base + i; if (idx < NN) s += cnt[idx]; }
  part[tid] = s;
  __syncthreads();
  for (int o = 1; o < 1024; o <<= 1) {
    int add = (tid >= o) ? part[tid - o] : 0;
    int v = part[tid];
    __syncthreads();
    part[tid] = v + add;
    __syncthreads();
  }
  int run = (tid == 0) ? 0 : part[tid - 1];
  for (int i = 0; i < CH; ++i) {
    int idx = base + i;
    if (idx < NN) { off[idx] = run; run += cnt[idx]; }
  }
  if (tid == 1023) off[NN] = ET;
}

__global__ __launch_bounds__(256) void k_scatter(const int* __restrict__ ei, const int* __restrict__ off,
                                                 int* __restrict__ cur, int* __restrict__ csrc) {
  for (int k = blockIdx.x * 256 + threadIdx.x; k < ET; k += gridDim.x * 256) {
    int s = (k < EE) ? ei[k]      : (k - EE);
    int d = (k < EE) ? ei[EE + k] : (k - EE);
    int p = atomicAdd(&cur[d], 1);
    csrc[off[d] + p] = s;
  }
}

// ---------------- f16 MFMA GEMM, generalized: C[M,NC] = A[M,K] @ B ----------------
// A: f16 row-major [M][K]; Bh/Bl: f16 TRANSPOSED [NC][K] hi/lo split.
// EPI 0: write f16, no bias. EPI 1: +bias, write f32. EPI 2: +bias, exact GELU, write f16.
template<int EPI>
__global__ __launch_bounds__(256) void k_mfma3(const __half* __restrict__ A,
                                               const __half* __restrict__ Bh,
                                               const __half* __restrict__ Bl,
                                               void* __restrict__ C,
                                               const float* __restrict__ bias,
                                               int M, int K, int NC) {
  __shared__ __half lds[3 * 128 * 64];   // A | Bh | Bl, 16 KB each
  __half* As  = lds;
  __half* Bhs = lds + 8192;
  __half* Bls = lds + 16384;
  const int tid = threadIdx.x, l = tid & 63, w = tid >> 6;
  const int wr = w >> 1, wc = w & 1;
  const int m0 = blockIdx.y * 128, n0 = blockIdx.x * 128;
  const int l15 = l & 15, l16 = l >> 4;
  const int sr = l >> 3;                 // staging sub-row 0..7
  const int ss = (l & 7) ^ sr;           // staging swizzled 16B slot

  f32x4 acc[4][4] = {};
  for (int k0 = 0; k0 < K; k0 += 64) {
#pragma unroll
    for (int j = 0; j < 4; ++j) {
      int rbase = j * 32 + w * 8;
      int rl = rbase + sr;
      int gA = min(m0 + rl, M - 1);
      int gB = n0 + rl;
      const size_t ko = (size_t)(k0 + ss * 8);
      ldg2lds16(A  + (size_t)gA * K + ko, As  + rbase * 64);
      ldg2lds16(Bh + (size_t)gB * K + ko, Bhs + rbase * 64);
      ldg2lds16(Bl + (size_t)gB * K + ko, Bls + rbase * 64);
    }
    __syncthreads();
#pragma unroll
    for (int kh = 0; kh < 2; ++kh) {
      half8 af[4], bhf[4], blf[4];
#pragma unroll
      for (int t = 0; t < 4; ++t) {
        int ra = wr * 64 + t * 16 + l15;
        int ca = (kh * 4 + l16) ^ (ra & 7);
        af[t] = *(const half8*)(As + ra * 64 + ca * 8);
        int rb = wc * 64 + t * 16 + l15;
        int cb = (kh * 4 + l16) ^ (rb & 7);
        bhf[t] = *(const half8*)(Bhs + rb * 64 + cb * 8);
        blf[t] = *(const half8*)(Bls + rb * 64 + cb * 8);
      }
#pragma unroll
      for (int i = 0; i < 4; ++i)
#pragma unroll
        for (int j = 0; j < 4; ++j) {
          acc[i][j] = __builtin_amdgcn_mfma_f32_16x16x32_f16(af[i], bhf[j], acc[i][j], 0, 0, 0);
          acc[i][j] = __builtin_amdgcn_mfma_f32_16x16x32_f16(af[i], blf[j], acc[i][j], 0, 0, 0);
        }
    }
    __syncthreads();
  }
#pragma unroll
  for (int i = 0; i < 4; ++i) {
#pragma unroll
    for (int r = 0; r < 4; ++r) {
      int row = m0 + wr * 64 + i * 16 + l16 * 4 + r;
      if (row >= M) continue;
#pragma unroll
      for (int j = 0; j < 4; ++j) {
        int col = n0 + wc * 64 + j * 16 + l15;
        float v = acc[i][j][r];
        if (EPI >= 1) v += bias[col];
        if (EPI == 2) v = 0.5f * v * (1.0f + erff(v * 0.70710678118654752f));
        if (EPI == 1) ((float*)C)[(size_t)row * NC + col] = v;
        else          ((__half*)C)[(size_t)row * NC + col] = __float2half(v);
      }
    }
  }
}

// ---------------- attention score dots from fp16 xp: s_src/s_dst [N,4] ----------------
__global__ __launch_bounds__(256) void k_sdots(const __half* __restrict__ xp16,
                                               const float* __restrict__ asw,
                                               const float* __restrict__ adw,
                                               float* __restrict__ ssrc, float* __restrict__ sdst) {
  int wv = threadIdx.x >> 6, ln = threadIdx.x & 63;
  int n = blockIdx.x * 4 + wv;
  int h = ln >> 4, c0 = (ln & 15) * 8;
  uint4 raw = *(const uint4*)(xp16 + (size_t)n * DD + h * 128 + c0);
  const __half2* hp = (const __half2*)&raw;
  float a = 0.f, b = 0.f;
#pragma unroll
  for (int j = 0; j < 4; ++j) {
    float2 f = __half22float2(hp[j]);
    a += f.x * asw[h * 128 + c0 + 2 * j]     + f.y * asw[h * 128 + c0 + 2 * j + 1];
    b += f.x * adw[h * 128 + c0 + 2 * j]     + f.y * adw[h * 128 + c0 + 2 * j + 1];
  }
#pragma unroll
  for (int o = 8; o; o >>= 1) { a += __shfl_xor(a, o); b += __shfl_xor(b, o); }
  if ((ln & 15) == 0) { ssrc[n * 4 + h] = a; sdst[n * 4 + h] = b; }
}

// ---------------- per-edge softmax weights (max-subtracted) into f32 SoA planes ----------------
__global__ __launch_bounds__(256) void k_eweight(const float* __restrict__ ssrc,
                                                 const float* __restrict__ sdst,
                                                 const int* __restrict__ off,
                                                 const int* __restrict__ csr,
                                                 float* __restrict__ ewp,
                                                 float* __restrict__ den) {
  int wv = threadIdx.x >> 6, ln = threadIdx.x & 63;
  int n = blockIdx.x * 4 + wv;
  int beg = off[n], end = off[n + 1];
  float4 sd4 = *(const float4*)(sdst + (size_t)n * 4);
  float m0 = -1e30f, m1 = -1e30f, m2 = -1e30f, m3 = -1e30f;
  for (int k = beg + ln; k < end; k += 64) {
    float4 s = *(const float4*)(ssrc + (size_t)csr[k] * 4);
    float e0 = s.x + sd4.x; e0 = (e0 > 0.f) ? e0 : 0.2f * e0; m0 = fmaxf(m0, e0);
    float e1 = s.y + sd4.y; e1 = (e1 > 0.f) ? e1 : 0.2f * e1; m1 = fmaxf(m1, e1);
    float e2 = s.z + sd4.z; e2 = (e2 > 0.f) ? e2 : 0.2f * e2; m2 = fmaxf(m2, e2);
    float e3 = s.w + sd4.w; e3 = (e3 > 0.f) ? e3 : 0.2f * e3; m3 = fmaxf(m3, e3);
  }
#pragma unroll
  for (int o = 32; o; o >>= 1) {
    m0 = fmaxf(m0, __shfl_xor(m0, o));
    m1 = fmaxf(m1, __shfl_xor(m1, o));
    m2 = fmaxf(m2, __shfl_xor(m2, o));
    m3 = fmaxf(m3, __shfl_xor(m3, o));
  }
  float d0 = 0.f, d1 = 0.f, d2 = 0.f, d3 = 0.f;
  for (int k = beg + ln; k < end; k += 64) {
    float4 s = *(const float4*)(ssrc + (size_t)csr[k] * 4);
    float e0 = s.x + sd4.x; e0 = (e0 > 0.f) ? e0 : 0.2f * e0;
    float e1 = s.y + sd4.y; e1 = (e1 > 0.f) ? e1 : 0.2f * e1;
    float e2 = s.z + sd4.z; e2 = (e2 > 0.f) ? e2 : 0.2f * e2;
    float e3 = s.w + sd4.w; e3 = (e3 > 0.f) ? e3 : 0.2f * e3;
    float w0 = __expf(e0 - m0), w1 = __expf(e1 - m1);
    float w2 = __expf(e2 - m2), w3 = __expf(e3 - m3);
    d0 += w0; d1 += w1; d2 += w2; d3 += w3;
    ewp[k]          = w0;
    ewp[ET + k]     = w1;
    ewp[2 * ET + k] = w2;
    ewp[3 * ET + k] = w3;
  }
#pragma unroll
  for (int o = 32; o; o >>= 1) {
    d0 += __shfl_xor(d0, o); d1 += __shfl_xor(d1, o);
    d2 += __shfl_xor(d2, o); d3 += __shfl_xor(d3, o);
  }
  if (ln == 0) *(float4*)(den + (size_t)n * 4) = make_float4(d0, d1, d2, d3);
}

// ---------------- channel-split aggregation (XCD-pinned slice; f16 residual stream) ----------------
// cb = blockIdx % 8 pins a 64-channel slice (2.56 MB of xp16) to one XCD's L2.
// One node per wave; scalarized edge stream (s_loads for csr/ew).
__global__ __launch_bounds__(256, 8) void k_aggc(const __half* __restrict__ xp16,
                                                 const float* __restrict__ ewp,
                                                 const float* __restrict__ den,
                                                 const int* __restrict__ off,
                                                 const int* __restrict__ csr,
                                                 const float* __restrict__ bias,
                                                 __half* __restrict__ xio,   // in: residual (f16), out: pre-LN (f16)
                                                 float* __restrict__ psq) {  // [NN][8][2]
  const int bid = blockIdx.x;
  const int cb = bid & 7;        // XCD-pinned channel block (HW round-robins blockIdx % 8)
  const int chunk = bid >> 3;    // node chunk of 4 (one node per wave)
  const int wv = threadIdx.x >> 6, ln = threadIdx.x & 63;
  const int c = cb * 64 + ln;
  const int h = cb >> 1;
  const float bi = bias[c];
  const float* __restrict__ ewh = ewp + (size_t)h * ET;

  const int n = __builtin_amdgcn_readfirstlane(chunk * 4 + wv);
  const int beg = off[n], end = off[n + 1];
  float acc = 0.f;
  int k = beg;
  for (; k + 8 <= end; k += 8) {
    int sk[8];
#pragma unroll
    for (int u = 0; u < 8; ++u) sk[u] = csr[k + u];          // scalar s_load
    float w[8];
#pragma unroll
    for (int u = 0; u < 8; ++u) w[u] = ewh[k + u];           // scalar s_load
    float x[8];
#pragma unroll
    for (int u = 0; u < 8; ++u) x[u] = __half2float(xp16[(size_t)sk[u] * DD + c]);
#pragma unroll
    for (int u = 0; u < 8; ++u) acc = fmaf(w[u], x[u], acc);
  }
  for (; k < end; ++k) {
    float x = __half2float(xp16[(size_t)csr[k] * DD + c]);
    acc = fmaf(ewh[k], x, acc);
  }
  float o = acc / den[(size_t)n * 4 + h] + bi + __half2float(xio[(size_t)n * DD + c]);
  xio[(size_t)n * DD + c] = __float2half_rn(o);
  float ps = o, pq = o * o;
#pragma unroll
  for (int oo = 32; oo; oo >>= 1) { ps += __shfl_xor(ps, oo); pq += __shfl_xor(pq, oo); }
  if (ln == 0) {
    psq[(size_t)n * 16 + cb * 2]     = ps;
    psq[(size_t)n * 16 + cb * 2 + 1] = pq;
  }
}

// ---------------- per-graph LN stats from psq (batch sorted; binary search range) ----------------
__device__ __forceinline__ int lowb(const int* a, int n, int key) {
  int lo = 0, hi = n;
  while (lo < hi) { int mid = (lo + hi) >> 1; if (a[mid] < key) lo = mid + 1; else hi = mid; }
  return lo;
}

__global__ __launch_bounds__(256) void k_stats2(const float* __restrict__ psq,
                                                const int* __restrict__ batch,
                                                float* __restrict__ gmu, float* __restrict__ grstd) {
  int g = blockIdx.x, tid = threadIdx.x;
  __shared__ int sb, se;
  __shared__ float rs[4], rq[4];
  if (tid == 0) { sb = lowb(batch, NN, g); se = lowb(batch, NN, g + 1); }
  __syncthreads();
  int b = sb, e = se;
  float ps = 0.f, pq = 0.f;
  for (int n = b + tid; n < e; n += 256) {
    const float4* p = (const float4*)(psq + (size_t)n * 16);
#pragma unroll
    for (int i = 0; i < 4; ++i) {
      float4 v = p[i];
      ps += v.x + v.z;
      pq += v.y + v.w;
    }
  }
#pragma unroll
  for (int o = 32; o; o >>= 1) { ps += __shfl_xor(ps, o); pq += __shfl_xor(pq, o); }
  int wv = tid >> 6, ln = tid & 63;
  if (ln == 0) { rs[wv] = ps; rq[wv] = pq; }
  __syncthreads();
  if (tid == 0) {
    float S = rs[0] + rs[1] + rs[2] + rs[3];
    float Q = rq[0] + rq[1] + rq[2] + rq[3];
    float cnt = fmaxf((float)(e - b) * (float)DD, 1.0f);
    float mu  = S / cnt;
    float var = fmaxf(Q / cnt - mu * mu, 0.0f);
    gmu[g]   = mu;
    grstd[g] = rsqrtf(var + 1e-5f);
  }
}

// ---------------- graph-LN normalize, f16 in / f16 out ----------------
__global__ __launch_bounds__(256) void k_norm(__half* __restrict__ x, const int* __restrict__ batch,
                                              const float* __restrict__ gmu, const float* __restrict__ grstd,
                                              const float* __restrict__ lnw, const float* __restrict__ lnb) {
  for (int i8 = blockIdx.x * 256 + threadIdx.x; i8 < NN * DD / 8; i8 += gridDim.x * 256) {
    int i = i8 * 8;
    int n = i >> 9, d = i & 511;
    int g = batch[n];
    float mu = gmu[g], rs = grstd[g];
    uint4 raw = *(uint4*)(x + i);
    __half2* hp = (__half2*)&raw;
    float4 w0 = *(const float4*)(lnw + d);
    float4 w1 = *(const float4*)(lnw + d + 4);
    float4 b0 = *(const float4*)(lnb + d);
    float4 b1 = *(const float4*)(lnb + d + 4);
    float wv[8] = {w0.x,w0.y,w0.z,w0.w,w1.x,w1.y,w1.z,w1.w};
    float bv[8] = {b0.x,b0.y,b0.z,b0.w,b1.x,b1.y,b1.z,b1.w};
#pragma unroll
    for (int j = 0; j < 4; ++j) {
      float2 f = __half22float2(hp[j]);
      f.x = (f.x - mu) * rs * wv[2*j]   + bv[2*j];
      f.y = (f.y - mu) * rs * wv[2*j+1] + bv[2*j+1];
      hp[j] = __floats2half2_rn(f.x, f.y);
    }
    *(uint4*)(x + i) = raw;
  }
}

// ---------------- pooling: mean + max per graph -> f16 [G][1024] ----------------
__global__ __launch_bounds__(256) void k_pool(const __half* __restrict__ x, const int* __restrict__ batch,
                                              __half* __restrict__ pool16) {
  int g = blockIdx.x, tid = threadIdx.x;
  __shared__ int sb, se;
  if (tid == 0) { sb = lowb(batch, NN, g); se = lowb(batch, NN, g + 1); }
  __syncthreads();
  int b = sb, e = se;
  float s0 = 0.f, s1 = 0.f, m0 = -INFINITY, m1 = -INFINITY;
  for (int n = b; n < e; ++n) {
    float v0 = __half2float(x[(size_t)n * DD + tid]);
    float v1 = __half2float(x[(size_t)n * DD + tid + 256]);
    s0 += v0; s1 += v1;
    m0 = fmaxf(m0, v0); m1 = fmaxf(m1, v1);
  }
  int cnt = e - b;
  float inv = 1.0f / (float)(cnt > 0 ? cnt : 1);
  pool16[(size_t)g * 1024 + tid]             = __float2half_rn(s0 * inv);
  pool16[(size_t)g * 1024 + tid + 256]       = __float2half_rn(s1 * inv);
  pool16[(size_t)g * 1024 + 512 + tid]       = __float2half_rn((cnt > 0) ? m0 : 0.f);
  pool16[(size_t)g * 1024 + 512 + tid + 256] = __float2half_rn((cnt > 0) ? m1 : 0.f);
}

// ---------------- final row L2 normalize ----------------
__global__ __launch_bounds__(256) void k_l2(float* __restrict__ h) {
  int g = blockIdx.x, t = threadIdx.x;
  float v = h[(size_t)g * OUTD + t];
  float q = v * v;
#pragma unroll
  for (int o = 32; o; o >>= 1) q += __shfl_xor(q, o);
  __shared__ float w[4];
  int wv = t >> 6, ln = t & 63;
  if (ln == 0) w[wv] = q;
  __syncthreads();
  float tot = w[0] + w[1] + w[2] + w[3];
  float nrm = fmaxf(sqrtf(tot), 1e-12f);
  h[(size_t)g * OUTD + t] = v / nrm;
}

// ---------------- launcher ----------------
extern "C" void kernel_launch(void* const* d_in, const int* in_sizes, int n_in,
                              void* d_out, int out_size, void* d_ws, size_t ws_size,
                              hipStream_t stream) {
  const int*   node_ids = (const int*)d_in[0];
  const int*   ei       = (const int*)d_in[1];
  const int*   batch    = (const int*)d_in[2];
  const float* emb      = (const float*)d_in[3];
  const float* W[4]  = {(const float*)d_in[4],  (const float*)d_in[10], (const float*)d_in[16], (const float*)d_in[22]};
  const float* AS[4] = {(const float*)d_in[5],  (const float*)d_in[11], (const float*)d_in[17], (const float*)d_in[23]};
  const float* AD[4] = {(const float*)d_in[6],  (const float*)d_in[12], (const float*)d_in[18], (const float*)d_in[24]};
  const float* BV[4] = {(const float*)d_in[7],  (const float*)d_in[13], (const float*)d_in[19], (const float*)d_in[25]};
  const float* LW[4] = {(const float*)d_in[8],  (const float*)d_in[14], (const float*)d_in[20], (const float*)d_in[26]};
  const float* LB[4] = {(const float*)d_in[9],  (const float*)d_in[15], (const float*)d_in[21], (const float*)d_in[27]};
  const float* res_w0 = (const float*)d_in[28];
  const float* p1w    = (const float*)d_in[29];
  const float* p1b    = (const float*)d_in[30];
  const float* p2w    = (const float*)d_in[31];
  const float* p2b    = (const float*)d_in[32];
  float* out = (float*)d_out;

  char* ws = (char*)d_ws;
  size_t pos = 0;
  auto alloc = [&](size_t bytes) -> char* {
    char* p = ws + pos;
    pos = (pos + bytes + 255) & ~size_t(255);
    return p;
  };
  __half* xr16  = (__half*)alloc((size_t)NN * DD * 2);   // unified residual / GEMM-A / pool input
  __half* xp16  = (__half*)alloc((size_t)NN * DD * 2);
  __half* x0f   = (__half*)alloc((size_t)NN * DEE * 2);
  float*  ssrc  = (float*)alloc((size_t)NN * 4 * 4);
  float*  sdst  = (float*)alloc((size_t)NN * 4 * 4);
  int*    coff  = (int*)alloc((size_t)(NN + 1) * 4);
  int*    ccur  = (int*)alloc((size_t)NN * 4);
  int*    csrc  = (int*)alloc((size_t)ET * 4);
  float*  ewp   = (float*)alloc((size_t)ET * 4 * 4);     // 4 head planes, f32
  float*  den   = (float*)alloc((size_t)NN * 4 * 4);
  float*  psq   = (float*)alloc((size_t)NN * 16 * 4);
  float*  gmu   = (float*)alloc((size_t)GG * 4 * 2);
  float*  grstd = gmu + GG;
  // transposed f16 hi/lo weights
  __half* w0th = (__half*)alloc((size_t)DEE * DD * 2); __half* w0tl = (__half*)alloc((size_t)DEE * DD * 2);
  __half* rwth = (__half*)alloc((size_t)DEE * DD * 2); __half* rwtl = (__half*)alloc((size_t)DEE * DD * 2);
  __half* wth[4] = {w0th, nullptr, nullptr, nullptr};
  __half* wtl[4] = {w0tl, nullptr, nullptr, nullptr};
  for (int i = 1; i < 4; ++i) {
    wth[i] = (__half*)alloc((size_t)DD * DD * 2);
    wtl[i] = (__half*)alloc((size_t)DD * DD * 2);
  }
  __half* p1th = (__half*)alloc((size_t)1024 * 1024 * 2);
  __half* p1tl = (__half*)alloc((size_t)1024 * 1024 * 2);
  __half* p2th = (__half*)alloc((size_t)OUTD * 1024 * 2);
  __half* p2tl = (__half*)alloc((size_t)OUTD * 1024 * 2);
  __half* pool16 = (__half*)alloc((size_t)GG * 1024 * 2);
  __half* h1_16  = (__half*)alloc((size_t)GG * 1024 * 2);
  (void)ws_size; (void)in_sizes; (void)n_in; (void)out_size;

  // ---- CSR + weight prep ----
  hipMemsetAsync(ccur, 0, (size_t)NN * 4, stream);
  k_embf16<<<1250, 256, 0, stream>>>(node_ids, emb, x0f);
  k_count<<<1024, 256, 0, stream>>>(ei, ccur);
  k_scan<<<1, 1024, 0, stream>>>(ccur, coff);
  hipMemsetAsync(ccur, 0, (size_t)NN * 4, stream);
  k_scatter<<<1024, 256, 0, stream>>>(ei, coff, ccur, csrc);
  k_wsplit16T<<<dim3(16, 2),  256, 0, stream>>>(W[0],   w0th, w0tl, DEE, DD);
  k_wsplit16T<<<dim3(16, 2),  256, 0, stream>>>(res_w0, rwth, rwtl, DEE, DD);
  for (int i = 1; i < 4; ++i)
    k_wsplit16T<<<dim3(16, 16), 256, 0, stream>>>(W[i], wth[i], wtl[i], DD, DD);
  k_wsplit16T<<<dim3(32, 32), 256, 0, stream>>>(p1w, p1th, p1tl, 1024, 1024);
  k_wsplit16T<<<dim3(8, 32),  256, 0, stream>>>(p2w, p2th, p2tl, 1024, OUTD);

  // ---- L0 projections ----
  k_mfma3<0><<<dim3(4, 157), 256, 0, stream>>>(x0f, w0th, w0tl, xp16, nullptr, NN, DEE, DD);
  k_mfma3<0><<<dim3(4, 157), 256, 0, stream>>>(x0f, rwth, rwtl, xr16, nullptr, NN, DEE, DD);

  // ---- 4 GAT layers ----
  for (int L = 0; L < 4; ++L) {
    k_sdots<<<NN / 4, 256, 0, stream>>>(xp16, AS[L], AD[L], ssrc, sdst);
    k_eweight<<<NN / 4, 256, 0, stream>>>(ssrc, sdst, coff, csrc, ewp, den);
    k_aggc<<<NN * 2, 256, 0, stream>>>(xp16, ewp, den, coff, csrc, BV[L], xr16, psq);
    k_stats2<<<GG, 256, 0, stream>>>(psq, batch, gmu, grstd);
    k_norm<<<2048, 256, 0, stream>>>(xr16, batch, gmu, grstd, LW[L], LB[L]);
    if (L < 3)
      k_mfma3<0><<<dim3(4, 157), 256, 0, stream>>>(xr16, wth[L + 1], wtl[L + 1], xp16, nullptr, NN, DD, DD);
  }

  // ---- pool + MLP head + normalize ----
  k_pool<<<GG, 256, 0, stream>>>(xr16, batch, pool16);
  k_mfma3<2><<<dim3(8, 1), 256, 0, stream>>>(pool16, p1th, p1tl, h1_16, p1b, GG, 1024, 1024);
  k_mfma3<1><<<dim3(2, 1), 256, 0, stream>>>(h1_16, p2th, p2tl, out,   p2b, GG, 1024, OUTD);
  k_l2<<<GG, 256, 0, stream>>>(out);
}

// Round 9
// 693.970 us; speedup vs baseline: 1.5687x; 1.0956x over previous
//
#include <hip/hip_runtime.h>
#include <hip/hip_fp16.h>
#include <math.h>

constexpr int NN   = 20000;
constexpr int EE   = 320000;
constexpr int ET   = EE + NN;   // 340000 with self loops
constexpr int GG   = 128;
constexpr int DEE  = 64;
constexpr int DD   = 512;
constexpr int OUTD = 256;

using half8 = __attribute__((ext_vector_type(8))) _Float16;
using f32x4 = __attribute__((ext_vector_type(4))) float;

// ---- async global->LDS 16B (wave-uniform LDS base + lane*16 implicit) ----
__device__ __forceinline__ void ldg2lds16(const void* g, void* l) {
  __builtin_amdgcn_global_load_lds((const __attribute__((address_space(1))) unsigned*)g,
                                   (__attribute__((address_space(3))) unsigned*)l, 16, 0, 0);
}

// ---------------- embedding gather -> f16 ----------------
__global__ __launch_bounds__(256) void k_embf16(const int* __restrict__ ids,
                                                const float* __restrict__ emb,
                                                __half* __restrict__ x0) {
  for (int i = blockIdx.x * 256 + threadIdx.x; i < NN * 16; i += gridDim.x * 256) {
    int n = i >> 4, q = (i & 15) * 4;
    float4 v = *(const float4*)(emb + (size_t)ids[n] * DEE + q);
    __half2* o = (__half2*)(x0 + (size_t)n * DEE + q);
    o[0] = __floats2half2_rn(v.x, v.y);
    o[1] = __floats2half2_rn(v.z, v.w);
  }
}

// ---------------- weight transpose + f16 hi/lo split: T[n][k] = W[k][n] ----------------
__global__ __launch_bounds__(256) void k_wsplit16T(const float* __restrict__ W,
                                                   __half* __restrict__ Th, __half* __restrict__ Tl,
                                                   int K, int N) {
  __shared__ float t[32][33];
  int n0 = blockIdx.x * 32, k0 = blockIdx.y * 32;
  int c = threadIdx.x & 31, r4 = threadIdx.x >> 5;
  for (int rr = 0; rr < 32; rr += 8)
    t[rr + r4][c] = W[(size_t)(k0 + rr + r4) * N + n0 + c];
  __syncthreads();
  for (int rr = 0; rr < 32; rr += 8) {
    int n = n0 + rr + r4, k = k0 + c;
    float v = t[c][rr + r4];
    __half hi = __float2half_rn(v);
    Th[(size_t)n * K + k] = hi;
    Tl[(size_t)n * K + k] = __float2half_rn(v - __half2float(hi));
  }
}

// ---------------- CSR build ----------------
__global__ __launch_bounds__(256) void k_count(const int* __restrict__ ei, int* __restrict__ cnt) {
  for (int k = blockIdx.x * 256 + threadIdx.x; k < ET; k += gridDim.x * 256) {
    int d = (k < EE) ? ei[EE + k] : (k - EE);
    atomicAdd(&cnt[d], 1);
  }
}

__global__ __launch_bounds__(1024) void k_scan(const int* __restrict__ cnt, int* __restrict__ off) {
  __shared__ int part[1024];
  int tid = threadIdx.x;
  constexpr int CH = (NN + 1023) / 1024;  // 20
  int base = tid * CH;
  int s = 0;
  for (int i = 0; i < CH; ++i) { int idx = base + i; if (idx < NN) s += cnt[idx]; }
  part[tid] = s;
  __syncthreads();
  for (int o = 1; o < 1024; o <<= 1) {
    int add = (tid >= o) ? part[tid - o] : 0;
    int v = part[tid];
    __syncthreads();
    part[tid] = v + add;
    __syncthreads();
  }
  int run = (tid == 0) ? 0 : part[tid - 1];
  for (int i = 0; i < CH; ++i) {
    int idx = base + i;
    if (idx < NN) { off[idx] = run; run += cnt[idx]; }
  }
  if (tid == 1023) off[NN] = ET;
}

__global__ __launch_bounds__(256) void k_scatter(const int* __restrict__ ei, const int* __restrict__ off,
                                                 int* __restrict__ cur, int* __restrict__ csrc) {
  for (int k = blockIdx.x * 256 + threadIdx.x; k < ET; k += gridDim.x * 256) {
    int s = (k < EE) ? ei[k]      : (k - EE);
    int d = (k < EE) ? ei[EE + k] : (k - EE);
    int p = atomicAdd(&cur[d], 1);
    csrc[off[d] + p] = s;
  }
}

// ---------------- f16 MFMA GEMM (layers): C[M,NC] = A[M,K] @ B, f16 out ----------------
__global__ __launch_bounds__(256) void k_mfma3(const __half* __restrict__ A,
                                               const __half* __restrict__ Bh,
                                               const __half* __restrict__ Bl,
                                               __half* __restrict__ C,
                                               int M, int K, int NC) {
  __shared__ __half lds[3 * 128 * 64];   // A | Bh | Bl, 16 KB each
  __half* As  = lds;
  __half* Bhs = lds + 8192;
  __half* Bls = lds + 16384;
  const int tid = threadIdx.x, l = tid & 63, w = tid >> 6;
  const int wr = w >> 1, wc = w & 1;
  const int m0 = blockIdx.y * 128, n0 = blockIdx.x * 128;
  const int l15 = l & 15, l16 = l >> 4;
  const int sr = l >> 3;
  const int ss = (l & 7) ^ sr;

  f32x4 acc[4][4] = {};
  for (int k0 = 0; k0 < K; k0 += 64) {
#pragma unroll
    for (int j = 0; j < 4; ++j) {
      int rbase = j * 32 + w * 8;
      int rl = rbase + sr;
      int gA = min(m0 + rl, M - 1);
      int gB = n0 + rl;
      const size_t ko = (size_t)(k0 + ss * 8);
      ldg2lds16(A  + (size_t)gA * K + ko, As  + rbase * 64);
      ldg2lds16(Bh + (size_t)gB * K + ko, Bhs + rbase * 64);
      ldg2lds16(Bl + (size_t)gB * K + ko, Bls + rbase * 64);
    }
    __syncthreads();
#pragma unroll
    for (int kh = 0; kh < 2; ++kh) {
      half8 af[4], bhf[4], blf[4];
#pragma unroll
      for (int t = 0; t < 4; ++t) {
        int ra = wr * 64 + t * 16 + l15;
        int ca = (kh * 4 + l16) ^ (ra & 7);
        af[t] = *(const half8*)(As + ra * 64 + ca * 8);
        int rb = wc * 64 + t * 16 + l15;
        int cb = (kh * 4 + l16) ^ (rb & 7);
        bhf[t] = *(const half8*)(Bhs + rb * 64 + cb * 8);
        blf[t] = *(const half8*)(Bls + rb * 64 + cb * 8);
      }
#pragma unroll
      for (int i = 0; i < 4; ++i)
#pragma unroll
        for (int j = 0; j < 4; ++j) {
          acc[i][j] = __builtin_amdgcn_mfma_f32_16x16x32_f16(af[i], bhf[j], acc[i][j], 0, 0, 0);
          acc[i][j] = __builtin_amdgcn_mfma_f32_16x16x32_f16(af[i], blf[j], acc[i][j], 0, 0, 0);
        }
    }
    __syncthreads();
  }
#pragma unroll
  for (int i = 0; i < 4; ++i) {
#pragma unroll
    for (int r = 0; r < 4; ++r) {
      int row = m0 + wr * 64 + i * 16 + l16 * 4 + r;
      if (row >= M) continue;
#pragma unroll
      for (int j = 0; j < 4; ++j) {
        int col = n0 + wc * 64 + j * 16 + l15;
        C[(size_t)row * NC + col] = __float2half(acc[i][j][r]);
      }
    }
  }
}

// ---------------- split-K MFMA partial GEMM (MLP head): part[kz][M][NC] f32 ----------------
__global__ __launch_bounds__(256) void k_mfmaK(const __half* __restrict__ A,
                                               const __half* __restrict__ Bh,
                                               const __half* __restrict__ Bl,
                                               float* __restrict__ part,
                                               int M, int K, int NC, int Kc) {
  __shared__ __half lds[3 * 128 * 64];
  __half* As  = lds;
  __half* Bhs = lds + 8192;
  __half* Bls = lds + 16384;
  const int tid = threadIdx.x, l = tid & 63, w = tid >> 6;
  const int wr = w >> 1, wc = w & 1;
  const int m0 = blockIdx.y * 128, n0 = blockIdx.x * 128;
  const int kz = blockIdx.z;
  const int kb = kz * Kc, ke = kb + Kc;
  const int l15 = l & 15, l16 = l >> 4;
  const int sr = l >> 3;
  const int ss = (l & 7) ^ sr;

  f32x4 acc[4][4] = {};
  for (int k0 = kb; k0 < ke; k0 += 64) {
#pragma unroll
    for (int j = 0; j < 4; ++j) {
      int rbase = j * 32 + w * 8;
      int rl = rbase + sr;
      int gA = min(m0 + rl, M - 1);
      int gB = n0 + rl;
      const size_t ko = (size_t)(k0 + ss * 8);
      ldg2lds16(A  + (size_t)gA * K + ko, As  + rbase * 64);
      ldg2lds16(Bh + (size_t)gB * K + ko, Bhs + rbase * 64);
      ldg2lds16(Bl + (size_t)gB * K + ko, Bls + rbase * 64);
    }
    __syncthreads();
#pragma unroll
    for (int kh = 0; kh < 2; ++kh) {
      half8 af[4], bhf[4], blf[4];
#pragma unroll
      for (int t = 0; t < 4; ++t) {
        int ra = wr * 64 + t * 16 + l15;
        int ca = (kh * 4 + l16) ^ (ra & 7);
        af[t] = *(const half8*)(As + ra * 64 + ca * 8);
        int rb = wc * 64 + t * 16 + l15;
        int cb = (kh * 4 + l16) ^ (rb & 7);
        bhf[t] = *(const half8*)(Bhs + rb * 64 + cb * 8);
        blf[t] = *(const half8*)(Bls + rb * 64 + cb * 8);
      }
#pragma unroll
      for (int i = 0; i < 4; ++i)
#pragma unroll
        for (int j = 0; j < 4; ++j) {
          acc[i][j] = __builtin_amdgcn_mfma_f32_16x16x32_f16(af[i], bhf[j], acc[i][j], 0, 0, 0);
          acc[i][j] = __builtin_amdgcn_mfma_f32_16x16x32_f16(af[i], blf[j], acc[i][j], 0, 0, 0);
        }
    }
    __syncthreads();
  }
  float* pz = part + (size_t)kz * M * NC;
#pragma unroll
  for (int i = 0; i < 4; ++i) {
#pragma unroll
    for (int r = 0; r < 4; ++r) {
      int row = m0 + wr * 64 + i * 16 + l16 * 4 + r;
      if (row >= M) continue;
#pragma unroll
      for (int j = 0; j < 4; ++j) {
        int col = n0 + wc * 64 + j * 16 + l15;
        pz[(size_t)row * NC + col] = acc[i][j][r];
      }
    }
  }
}

// ---------------- finalize p1: sum 8 partials + bias + GELU -> f16 ----------------
__global__ __launch_bounds__(256) void k_fin_gelu(const float* __restrict__ part,
                                                  const float* __restrict__ bias,
                                                  __half* __restrict__ outh) {
  int idx = blockIdx.x * 256 + threadIdx.x;   // [GG*1024)
  if (idx >= GG * 1024) return;
  int c = idx & 1023;
  float v = bias[c];
#pragma unroll
  for (int z = 0; z < 8; ++z) v += part[(size_t)z * GG * 1024 + idx];
  v = 0.5f * v * (1.0f + erff(v * 0.70710678118654752f));
  outh[idx] = __float2half_rn(v);
}

// ---------------- finalize p2 + row L2 normalize: one block per graph ----------------
__global__ __launch_bounds__(256) void k_fin_l2(const float* __restrict__ part,
                                                const float* __restrict__ bias,
                                                float* __restrict__ out) {
  int g = blockIdx.x, t = threadIdx.x;   // t < 256 = OUTD
  float v = bias[t];
#pragma unroll
  for (int z = 0; z < 8; ++z) v += part[(size_t)z * GG * OUTD + g * OUTD + t];
  float q = v * v;
#pragma unroll
  for (int o = 32; o; o >>= 1) q += __shfl_xor(q, o);
  __shared__ float w[4];
  int wv = t >> 6, ln = t & 63;
  if (ln == 0) w[wv] = q;
  __syncthreads();
  float tot = w[0] + w[1] + w[2] + w[3];
  float nrm = fmaxf(sqrtf(tot), 1e-12f);
  out[(size_t)g * OUTD + t] = v / nrm;
}

// ---------------- attention score dots from fp16 xp: s_src/s_dst [N,4] ----------------
__global__ __launch_bounds__(256) void k_sdots(const __half* __restrict__ xp16,
                                               const float* __restrict__ asw,
                                               const float* __restrict__ adw,
                                               float* __restrict__ ssrc, float* __restrict__ sdst) {
  int wv = threadIdx.x >> 6, ln = threadIdx.x & 63;
  int n = blockIdx.x * 4 + wv;
  int h = ln >> 4, c0 = (ln & 15) * 8;
  uint4 raw = *(const uint4*)(xp16 + (size_t)n * DD + h * 128 + c0);
  const __half2* hp = (const __half2*)&raw;
  float a = 0.f, b = 0.f;
#pragma unroll
  for (int j = 0; j < 4; ++j) {
    float2 f = __half22float2(hp[j]);
    a += f.x * asw[h * 128 + c0 + 2 * j]     + f.y * asw[h * 128 + c0 + 2 * j + 1];
    b += f.x * adw[h * 128 + c0 + 2 * j]     + f.y * adw[h * 128 + c0 + 2 * j + 1];
  }
#pragma unroll
  for (int o = 8; o; o >>= 1) { a += __shfl_xor(a, o); b += __shfl_xor(b, o); }
  if ((ln & 15) == 0) { ssrc[n * 4 + h] = a; sdst[n * 4 + h] = b; }
}

// ---------------- per-edge softmax weights (max-subtracted) into f32 SoA planes ----------------
__global__ __launch_bounds__(256) void k_eweight(const float* __restrict__ ssrc,
                                                 const float* __restrict__ sdst,
                                                 const int* __restrict__ off,
                                                 const int* __restrict__ csr,
                                                 float* __restrict__ ewp,
                                                 float* __restrict__ den) {
  int wv = threadIdx.x >> 6, ln = threadIdx.x & 63;
  int n = blockIdx.x * 4 + wv;
  int beg = off[n], end = off[n + 1];
  float4 sd4 = *(const float4*)(sdst + (size_t)n * 4);
  float m0 = -1e30f, m1 = -1e30f, m2 = -1e30f, m3 = -1e30f;
  for (int k = beg + ln; k < end; k += 64) {
    float4 s = *(const float4*)(ssrc + (size_t)csr[k] * 4);
    float e0 = s.x + sd4.x; e0 = (e0 > 0.f) ? e0 : 0.2f * e0; m0 = fmaxf(m0, e0);
    float e1 = s.y + sd4.y; e1 = (e1 > 0.f) ? e1 : 0.2f * e1; m1 = fmaxf(m1, e1);
    float e2 = s.z + sd4.z; e2 = (e2 > 0.f) ? e2 : 0.2f * e2; m2 = fmaxf(m2, e2);
    float e3 = s.w + sd4.w; e3 = (e3 > 0.f) ? e3 : 0.2f * e3; m3 = fmaxf(m3, e3);
  }
#pragma unroll
  for (int o = 32; o; o >>= 1) {
    m0 = fmaxf(m0, __shfl_xor(m0, o));
    m1 = fmaxf(m1, __shfl_xor(m1, o));
    m2 = fmaxf(m2, __shfl_xor(m2, o));
    m3 = fmaxf(m3, __shfl_xor(m3, o));
  }
  float d0 = 0.f, d1 = 0.f, d2 = 0.f, d3 = 0.f;
  for (int k = beg + ln; k < end; k += 64) {
    float4 s = *(const float4*)(ssrc + (size_t)csr[k] * 4);
    float e0 = s.x + sd4.x; e0 = (e0 > 0.f) ? e0 : 0.2f * e0;
    float e1 = s.y + sd4.y; e1 = (e1 > 0.f) ? e1 : 0.2f * e1;
    float e2 = s.z + sd4.z; e2 = (e2 > 0.f) ? e2 : 0.2f * e2;
    float e3 = s.w + sd4.w; e3 = (e3 > 0.f) ? e3 : 0.2f * e3;
    float w0 = __expf(e0 - m0), w1 = __expf(e1 - m1);
    float w2 = __expf(e2 - m2), w3 = __expf(e3 - m3);
    d0 += w0; d1 += w1; d2 += w2; d3 += w3;
    ewp[k]          = w0;
    ewp[ET + k]     = w1;
    ewp[2 * ET + k] = w2;
    ewp[3 * ET + k] = w3;
  }
#pragma unroll
  for (int o = 32; o; o >>= 1) {
    d0 += __shfl_xor(d0, o); d1 += __shfl_xor(d1, o);
    d2 += __shfl_xor(d2, o); d3 += __shfl_xor(d3, o);
  }
  if (ln == 0) *(float4*)(den + (size_t)n * 4) = make_float4(d0, d1, d2, d3);
}

// ---------------- channel-split aggregation (XCD-pinned slice; unroll-16 MLP) ----------------
__global__ __launch_bounds__(256, 8) void k_aggc(const __half* __restrict__ xp16,
                                                 const float* __restrict__ ewp,
                                                 const float* __restrict__ den,
                                                 const int* __restrict__ off,
                                                 const int* __restrict__ csr,
                                                 const float* __restrict__ bias,
                                                 __half* __restrict__ xio,   // in: residual (f16), out: pre-LN (f16)
                                                 float* __restrict__ psq) {  // [NN][8][2]
  const int bid = blockIdx.x;
  const int cb = bid & 7;        // XCD-pinned channel block (HW round-robins blockIdx % 8)
  const int chunk = bid >> 3;    // node chunk of 4 (one node per wave)
  const int wv = threadIdx.x >> 6, ln = threadIdx.x & 63;
  const int c = cb * 64 + ln;
  const int h = cb >> 1;
  const float bi = bias[c];
  const float* __restrict__ ewh = ewp + (size_t)h * ET;

  const int n = __builtin_amdgcn_readfirstlane(chunk * 4 + wv);
  const int beg = off[n], end = off[n + 1];
  float acc = 0.f;
  int k = beg;
  for (; k + 16 <= end; k += 16) {
    int sk[16];
#pragma unroll
    for (int u = 0; u < 16; ++u) sk[u] = csr[k + u];         // scalar s_load x8
    float w[16];
#pragma unroll
    for (int u = 0; u < 16; ++u) w[u] = ewh[k + u];          // scalar s_load x8
    float x[16];
#pragma unroll
    for (int u = 0; u < 16; ++u) x[u] = __half2float(xp16[(size_t)sk[u] * DD + c]);
#pragma unroll
    for (int u = 0; u < 16; ++u) acc = fmaf(w[u], x[u], acc);
  }
  if (k + 8 <= end) {
    int sk[8];
#pragma unroll
    for (int u = 0; u < 8; ++u) sk[u] = csr[k + u];
    float w[8];
#pragma unroll
    for (int u = 0; u < 8; ++u) w[u] = ewh[k + u];
    float x[8];
#pragma unroll
    for (int u = 0; u < 8; ++u) x[u] = __half2float(xp16[(size_t)sk[u] * DD + c]);
#pragma unroll
    for (int u = 0; u < 8; ++u) acc = fmaf(w[u], x[u], acc);
    k += 8;
  }
  for (; k < end; ++k) {
    float x = __half2float(xp16[(size_t)csr[k] * DD + c]);
    acc = fmaf(ewh[k], x, acc);
  }
  float o = acc / den[(size_t)n * 4 + h] + bi + __half2float(xio[(size_t)n * DD + c]);
  xio[(size_t)n * DD + c] = __float2half_rn(o);
  float ps = o, pq = o * o;
#pragma unroll
  for (int oo = 32; oo; oo >>= 1) { ps += __shfl_xor(ps, oo); pq += __shfl_xor(pq, oo); }
  if (ln == 0) {
    psq[(size_t)n * 16 + cb * 2]     = ps;
    psq[(size_t)n * 16 + cb * 2 + 1] = pq;
  }
}

// ---------------- per-graph LN stats from psq (batch sorted; binary search range) ----------------
__device__ __forceinline__ int lowb(const int* a, int n, int key) {
  int lo = 0, hi = n;
  while (lo < hi) { int mid = (lo + hi) >> 1; if (a[mid] < key) lo = mid + 1; else hi = mid; }
  return lo;
}

__global__ __launch_bounds__(256) void k_stats2(const float* __restrict__ psq,
                                                const int* __restrict__ batch,
                                                float* __restrict__ gmu, float* __restrict__ grstd) {
  int g = blockIdx.x, tid = threadIdx.x;
  __shared__ int sb, se;
  __shared__ float rs[4], rq[4];
  if (tid == 0) { sb = lowb(batch, NN, g); se = lowb(batch, NN, g + 1); }
  __syncthreads();
  int b = sb, e = se;
  float ps = 0.f, pq = 0.f;
  for (int n = b + tid; n < e; n += 256) {
    const float4* p = (const float4*)(psq + (size_t)n * 16);
#pragma unroll
    for (int i = 0; i < 4; ++i) {
      float4 v = p[i];
      ps += v.x + v.z;
      pq += v.y + v.w;
    }
  }
#pragma unroll
  for (int o = 32; o; o >>= 1) { ps += __shfl_xor(ps, o); pq += __shfl_xor(pq, o); }
  int wv = tid >> 6, ln = tid & 63;
  if (ln == 0) { rs[wv] = ps; rq[wv] = pq; }
  __syncthreads();
  if (tid == 0) {
    float S = rs[0] + rs[1] + rs[2] + rs[3];
    float Q = rq[0] + rq[1] + rq[2] + rq[3];
    float cnt = fmaxf((float)(e - b) * (float)DD, 1.0f);
    float mu  = S / cnt;
    float var = fmaxf(Q / cnt - mu * mu, 0.0f);
    gmu[g]   = mu;
    grstd[g] = rsqrtf(var + 1e-5f);
  }
}

// ---------------- graph-LN normalize, f16 in / f16 out ----------------
__global__ __launch_bounds__(256) void k_norm(__half* __restrict__ x, const int* __restrict__ batch,
                                              const float* __restrict__ gmu, const float* __restrict__ grstd,
                                              const float* __restrict__ lnw, const float* __restrict__ lnb) {
  for (int i8 = blockIdx.x * 256 + threadIdx.x; i8 < NN * DD / 8; i8 += gridDim.x * 256) {
    int i = i8 * 8;
    int n = i >> 9, d = i & 511;
    int g = batch[n];
    float mu = gmu[g], rs = grstd[g];
    uint4 raw = *(uint4*)(x + i);
    __half2* hp = (__half2*)&raw;
    float4 w0 = *(const float4*)(lnw + d);
    float4 w1 = *(const float4*)(lnw + d + 4);
    float4 b0 = *(const float4*)(lnb + d);
    float4 b1 = *(const float4*)(lnb + d + 4);
    float wv[8] = {w0.x,w0.y,w0.z,w0.w,w1.x,w1.y,w1.z,w1.w};
    float bv[8] = {b0.x,b0.y,b0.z,b0.w,b1.x,b1.y,b1.z,b1.w};
#pragma unroll
    for (int j = 0; j < 4; ++j) {
      float2 f = __half22float2(hp[j]);
      f.x = (f.x - mu) * rs * wv[2*j]   + bv[2*j];
      f.y = (f.y - mu) * rs * wv[2*j+1] + bv[2*j+1];
      hp[j] = __floats2half2_rn(f.x, f.y);
    }
    *(uint4*)(x + i) = raw;
  }
}

// ---------------- pooling: mean + max per graph -> f16 [G][1024] ----------------
__global__ __launch_bounds__(256) void k_pool(const __half* __restrict__ x, const int* __restrict__ batch,
                                              __half* __restrict__ pool16) {
  int g = blockIdx.x, tid = threadIdx.x;
  __shared__ int sb, se;
  if (tid == 0) { sb = lowb(batch, NN, g); se = lowb(batch, NN, g + 1); }
  __syncthreads();
  int b = sb, e = se;
  float s0 = 0.f, s1 = 0.f, m0 = -INFINITY, m1 = -INFINITY;
  for (int n = b; n < e; ++n) {
    float v0 = __half2float(x[(size_t)n * DD + tid]);
    float v1 = __half2float(x[(size_t)n * DD + tid + 256]);
    s0 += v0; s1 += v1;
    m0 = fmaxf(m0, v0); m1 = fmaxf(m1, v1);
  }
  int cnt = e - b;
  float inv = 1.0f / (float)(cnt > 0 ? cnt : 1);
  pool16[(size_t)g * 1024 + tid]             = __float2half_rn(s0 * inv);
  pool16[(size_t)g * 1024 + tid + 256]       = __float2half_rn(s1 * inv);
  pool16[(size_t)g * 1024 + 512 + tid]       = __float2half_rn((cnt > 0) ? m0 : 0.f);
  pool16[(size_t)g * 1024 + 512 + tid + 256] = __float2half_rn((cnt > 0) ? m1 : 0.f);
}

// ---------------- launcher ----------------
extern "C" void kernel_launch(void* const* d_in, const int* in_sizes, int n_in,
                              void* d_out, int out_size, void* d_ws, size_t ws_size,
                              hipStream_t stream) {
  const int*   node_ids = (const int*)d_in[0];
  const int*   ei       = (const int*)d_in[1];
  const int*   batch    = (const int*)d_in[2];
  const float* emb      = (const float*)d_in[3];
  const float* W[4]  = {(const float*)d_in[4],  (const float*)d_in[10], (const float*)d_in[16], (const float*)d_in[22]};
  const float* AS[4] = {(const float*)d_in[5],  (const float*)d_in[11], (const float*)d_in[17], (const float*)d_in[23]};
  const float* AD[4] = {(const float*)d_in[6],  (const float*)d_in[12], (const float*)d_in[18], (const float*)d_in[24]};
  const float* BV[4] = {(const float*)d_in[7],  (const float*)d_in[13], (const float*)d_in[19], (const float*)d_in[25]};
  const float* LW[4] = {(const float*)d_in[8],  (const float*)d_in[14], (const float*)d_in[20], (const float*)d_in[26]};
  const float* LB[4] = {(const float*)d_in[9],  (const float*)d_in[15], (const float*)d_in[21], (const float*)d_in[27]};
  const float* res_w0 = (const float*)d_in[28];
  const float* p1w    = (const float*)d_in[29];
  const float* p1b    = (const float*)d_in[30];
  const float* p2w    = (const float*)d_in[31];
  const float* p2b    = (const float*)d_in[32];
  float* out = (float*)d_out;

  char* ws = (char*)d_ws;
  size_t pos = 0;
  auto alloc = [&](size_t bytes) -> char* {
    char* p = ws + pos;
    pos = (pos + bytes + 255) & ~size_t(255);
    return p;
  };
  __half* xr16  = (__half*)alloc((size_t)NN * DD * 2);   // unified residual / GEMM-A / pool input
  __half* xp16  = (__half*)alloc((size_t)NN * DD * 2);
  __half* x0f   = (__half*)alloc((size_t)NN * DEE * 2);
  float*  ssrc  = (float*)alloc((size_t)NN * 4 * 4);
  float*  sdst  = (float*)alloc((size_t)NN * 4 * 4);
  int*    coff  = (int*)alloc((size_t)(NN + 1) * 4);
  int*    ccur  = (int*)alloc((size_t)NN * 4);
  int*    csrc  = (int*)alloc((size_t)ET * 4);
  float*  ewp   = (float*)alloc((size_t)ET * 4 * 4);     // 4 head planes, f32
  float*  den   = (float*)alloc((size_t)NN * 4 * 4);
  float*  psq   = (float*)alloc((size_t)NN * 16 * 4);
  float*  gmu   = (float*)alloc((size_t)GG * 4 * 2);
  float*  grstd = gmu + GG;
  // transposed f16 hi/lo weights
  __half* w0th = (__half*)alloc((size_t)DEE * DD * 2); __half* w0tl = (__half*)alloc((size_t)DEE * DD * 2);
  __half* rwth = (__half*)alloc((size_t)DEE * DD * 2); __half* rwtl = (__half*)alloc((size_t)DEE * DD * 2);
  __half* wth[4] = {w0th, nullptr, nullptr, nullptr};
  __half* wtl[4] = {w0tl, nullptr, nullptr, nullptr};
  for (int i = 1; i < 4; ++i) {
    wth[i] = (__half*)alloc((size_t)DD * DD * 2);
    wtl[i] = (__half*)alloc((size_t)DD * DD * 2);
  }
  __half* p1th = (__half*)alloc((size_t)1024 * 1024 * 2);
  __half* p1tl = (__half*)alloc((size_t)1024 * 1024 * 2);
  __half* p2th = (__half*)alloc((size_t)OUTD * 1024 * 2);
  __half* p2tl = (__half*)alloc((size_t)OUTD * 1024 * 2);
  __half* pool16 = (__half*)alloc((size_t)GG * 1024 * 2);
  __half* h1_16  = (__half*)alloc((size_t)GG * 1024 * 2);
  float*  part1  = (float*)alloc((size_t)8 * GG * 1024 * 4);  // 4 MB
  float*  part2  = (float*)alloc((size_t)8 * GG * OUTD * 4);  // 1 MB
  (void)ws_size; (void)in_sizes; (void)n_in; (void)out_size;

  // ---- CSR + weight prep ----
  hipMemsetAsync(ccur, 0, (size_t)NN * 4, stream);
  k_embf16<<<1250, 256, 0, stream>>>(node_ids, emb, x0f);
  k_count<<<1024, 256, 0, stream>>>(ei, ccur);
  k_scan<<<1, 1024, 0, stream>>>(ccur, coff);
  hipMemsetAsync(ccur, 0, (size_t)NN * 4, stream);
  k_scatter<<<1024, 256, 0, stream>>>(ei, coff, ccur, csrc);
  k_wsplit16T<<<dim3(16, 2),  256, 0, stream>>>(W[0],   w0th, w0tl, DEE, DD);
  k_wsplit16T<<<dim3(16, 2),  256, 0, stream>>>(res_w0, rwth, rwtl, DEE, DD);
  for (int i = 1; i < 4; ++i)
    k_wsplit16T<<<dim3(16, 16), 256, 0, stream>>>(W[i], wth[i], wtl[i], DD, DD);
  k_wsplit16T<<<dim3(32, 32), 256, 0, stream>>>(p1w, p1th, p1tl, 1024, 1024);
  k_wsplit16T<<<dim3(8, 32),  256, 0, stream>>>(p2w, p2th, p2tl, 1024, OUTD);

  // ---- L0 projections ----
  k_mfma3<<<dim3(4, 157), 256, 0, stream>>>(x0f, w0th, w0tl, xp16, NN, DEE, DD);
  k_mfma3<<<dim3(4, 157), 256, 0, stream>>>(x0f, rwth, rwtl, xr16, NN, DEE, DD);

  // ---- 4 GAT layers ----
  for (int L = 0; L < 4; ++L) {
    k_sdots<<<NN / 4, 256, 0, stream>>>(xp16, AS[L], AD[L], ssrc, sdst);
    k_eweight<<<NN / 4, 256, 0, stream>>>(ssrc, sdst, coff, csrc, ewp, den);
    k_aggc<<<NN * 2, 256, 0, stream>>>(xp16, ewp, den, coff, csrc, BV[L], xr16, psq);
    k_stats2<<<GG, 256, 0, stream>>>(psq, batch, gmu, grstd);
    k_norm<<<2048, 256, 0, stream>>>(xr16, batch, gmu, grstd, LW[L], LB[L]);
    if (L < 3)
      k_mfma3<<<dim3(4, 157), 256, 0, stream>>>(xr16, wth[L + 1], wtl[L + 1], xp16, NN, DD, DD);
  }

  // ---- pool + MLP head (split-K) + fused finalize/normalize ----
  k_pool<<<GG, 256, 0, stream>>>(xr16, batch, pool16);
  k_mfmaK<<<dim3(8, 1, 8), 256, 0, stream>>>(pool16, p1th, p1tl, part1, GG, 1024, 1024, 128);
  k_fin_gelu<<<512, 256, 0, stream>>>(part1, p1b, h1_16);
  k_mfmaK<<<dim3(2, 1, 8), 256, 0, stream>>>(h1_16, p2th, p2tl, part2, GG, 1024, OUTD, 128);
  k_fin_l2<<<GG, 256, 0, stream>>>(part2, p2b, out);
}